// Round 1
// baseline (1402.539 us; speedup 1.0000x reference)
//
#include <hip/hip_runtime.h>
#include <math.h>

#define B_    16
#define N_    1024
#define DIM_  512
#define H_    8
#define HD_   64
#define SCALE_ 0.125f
#define PI_F  3.14159265358979323846f

// ---- workspace layout (float offsets) ----
static const size_t OFF_Q     = 0;         // (B,H,N,64)  8388608
static const size_t OFF_K     = 8388608;   // (B,H,N,64)
static const size_t OFF_V     = 16777216;  // (B,H,N,64)
static const size_t OFF_AO    = 25165824;  // (B,N,512)
static const size_t OFF_XMEAN = 33554432;  // (B,N)       16384
static const size_t OFF_XAVG  = 33570816;  // (B,512)     8192 (accumulated sums)
static const size_t OFF_D     = 33579008;  // (B,N)       16384 normalized dct feat
static const size_t OFF_T     = 33595392;  // (B)         16
static const size_t OFF_C     = 33595408;  // (B,N)       16384 row coefficient
// total = 33611792 floats = ~128.2 MiB

// ---------- x_mean over DIM (one wave per row) ----------
__global__ __launch_bounds__(256) void k_xmean(const float* __restrict__ x,
                                               float* __restrict__ xmean) {
  int row  = blockIdx.x * 4 + (threadIdx.x >> 6);
  int lane = threadIdx.x & 63;
  const float* px = x + (size_t)row * DIM_;
  float s = 0.f;
#pragma unroll
  for (int j = 0; j < DIM_ / 64; ++j) s += px[lane + j * 64];
  for (int off = 32; off; off >>= 1) s += __shfl_down(s, off);
  if (lane == 0) xmean[row] = s * (1.f / DIM_);
}

// ---------- x column sums over N (partial, atomic) ----------
__global__ __launch_bounds__(512) void k_xavg(const float* __restrict__ x,
                                              float* __restrict__ xavg) {
  int b = blockIdx.x, chunk = blockIdx.y;
  int c = threadIdx.x;
  const float* px = x + ((size_t)b * N_ + (size_t)chunk * 64) * DIM_ + c;
  float s = 0.f;
#pragma unroll 8
  for (int n = 0; n < 64; ++n) s += px[(size_t)n * DIM_];
  atomicAdd(&xavg[b * DIM_ + c], s);
}

// ---------- DCT-II feature: d = normalize(clip(D@A@D^T, +-10)), T = sum(d) ----------
__global__ __launch_bounds__(1024) void k_dct(const float* __restrict__ xmean,
                                              float* __restrict__ dfeat,
                                              float* __restrict__ tsum) {
  __shared__ float A[32][33], Dm[32][33], Tm[32][33];
  __shared__ float red[1024];
  __shared__ float nrm;
  int b = blockIdx.x, t = threadIdx.x;
  int kk = t >> 5, nn = t & 31;
  A[kk][nn] = xmean[b * N_ + t];
  float dv = (kk == 0) ? sqrtf(1.f / 32.f)
                       : sqrtf(2.f / 32.f) * cosf(PI_F * (2.f * nn + 1.f) * (float)kk / 64.f);
  Dm[kk][nn] = dv;
  __syncthreads();
  float acc = 0.f;
  for (int m = 0; m < 32; ++m) acc += Dm[kk][m] * A[m][nn];
  Tm[kk][nn] = acc;
  __syncthreads();
  float acc2 = 0.f;
  for (int n = 0; n < 32; ++n) acc2 += Tm[kk][n] * Dm[nn][n];
  float val = fminf(fmaxf(acc2, -10.f), 10.f);
  red[t] = val * val;
  __syncthreads();
  for (int s = 512; s; s >>= 1) { if (t < s) red[t] += red[t + s]; __syncthreads(); }
  if (t == 0) nrm = sqrtf(red[0]) + 1e-5f;
  __syncthreads();
  float dn = val / nrm;
  dfeat[b * N_ + t] = dn;
  red[t] = dn;
  __syncthreads();
  for (int s = 512; s; s >>= 1) { if (t < s) red[t] += red[t + s]; __syncthreads(); }
  if (t == 0) tsum[b] = red[0];
}

// ---------- head MLP -> s_b -> row coefficients c ----------
__global__ __launch_bounds__(128) void k_headw(const float* __restrict__ xavg,
                                               const float* __restrict__ h1w,
                                               const float* __restrict__ h1b,
                                               const float* __restrict__ h2w,
                                               const float* __restrict__ h2b,
                                               const float* __restrict__ dfeat,
                                               const float* __restrict__ tsum,
                                               float* __restrict__ crow) {
  __shared__ float xa[512];
  __shared__ float h1s[128];
  __shared__ float hw[8];
  int b = blockIdx.x, t = threadIdx.x;
  for (int i = t; i < 512; i += 128) xa[i] = xavg[b * DIM_ + i] * (1.f / N_);
  __syncthreads();
  float acc = h1b[t];
  for (int c = 0; c < 512; ++c) acc += xa[c] * h1w[c * 128 + t];
  h1s[t] = fmaxf(acc, 0.f);
  __syncthreads();
  if (t < 8) {
    float a2 = h2b[t];
    for (int j = 0; j < 128; ++j) a2 += h1s[j] * h2w[j * 8 + t];
    hw[t] = a2;
  }
  __syncthreads();
  float s = 0.f;
#pragma unroll
  for (int h = 0; h < 8; ++h) s += hw[h] * hw[h];
  float Tb = tsum[b];
  for (int n = t; n < N_; n += 128) {
    float dn = dfeat[b * N_ + n];
    float p = s * dn;
    float denom = fmaxf(p * Tb, 1e-5f);
    crow[b * N_ + n] = p / denom;
  }
}

// ---------- QKV GEMM: (16384x512)@(512x1536)+b -> q(*SCALE),k,v in (B,H,N,64) ----------
__global__ __launch_bounds__(256) void k_qkv(const float* __restrict__ x,
                                             const float* __restrict__ w,
                                             const float* __restrict__ bias,
                                             float* __restrict__ q,
                                             float* __restrict__ k,
                                             float* __restrict__ v) {
  __shared__ __align__(16) float As[16][68];
  __shared__ __align__(16) float Bs[16][68];
  const int t = threadIdx.x;
  const int row0 = blockIdx.y * 64;
  const int col0 = blockIdx.x * 64;
  const int tm = t >> 4, tn = t & 15;
  float acc[4][4] = {};
  for (int k0 = 0; k0 < DIM_; k0 += 16) {
    {
      int m = t >> 2;
      int kb = (t & 3) * 4;
      const float4 a4 = *(const float4*)(x + (size_t)(row0 + m) * DIM_ + k0 + kb);
      As[kb + 0][m] = a4.x; As[kb + 1][m] = a4.y; As[kb + 2][m] = a4.z; As[kb + 3][m] = a4.w;
    }
    {
      int kk = t >> 4;
      int nb = (t & 15) * 4;
      *(float4*)(&Bs[kk][nb]) = *(const float4*)(w + (size_t)(k0 + kk) * 1536 + col0 + nb);
    }
    __syncthreads();
#pragma unroll
    for (int kk = 0; kk < 16; ++kk) {
      float4 ra = *(const float4*)(&As[kk][tm * 4]);
      float4 rb = *(const float4*)(&Bs[kk][tn * 4]);
      float a[4] = {ra.x, ra.y, ra.z, ra.w};
      float bb[4] = {rb.x, rb.y, rb.z, rb.w};
#pragma unroll
      for (int i = 0; i < 4; ++i)
#pragma unroll
        for (int j = 0; j < 4; ++j) acc[i][j] += a[i] * bb[j];
    }
    __syncthreads();
  }
  const int sel = col0 >> 9;
  const int h = (col0 & 511) >> 6;
  float* dstbase = (sel == 0) ? q : (sel == 1) ? k : v;
  const float scl = (sel == 0) ? SCALE_ : 1.f;
  float bj[4];
#pragma unroll
  for (int j = 0; j < 4; ++j) bj[j] = bias[col0 + tn * 4 + j];
#pragma unroll
  for (int i = 0; i < 4; ++i) {
    int gm = row0 + tm * 4 + i;
    int bb = gm >> 10, n = gm & 1023;
    float4 o;
    o.x = (acc[i][0] + bj[0]) * scl;
    o.y = (acc[i][1] + bj[1]) * scl;
    o.z = (acc[i][2] + bj[2]) * scl;
    o.w = (acc[i][3] + bj[3]) * scl;
    *(float4*)(dstbase + (((size_t)bb * H_ + h) * N_ + n) * HD_ + tn * 4) = o;
  }
}

// ---------- flash attention with rank-1 freq bias ----------
__global__ __launch_bounds__(256) void k_attn(const float* __restrict__ qg,
                                              const float* __restrict__ kg,
                                              const float* __restrict__ vg,
                                              const float* __restrict__ crow,
                                              const float* __restrict__ dfeat,
                                              const float* __restrict__ freqw,
                                              float* __restrict__ ao) {
  __shared__ __align__(16) float Qs[64][68];
  __shared__ __align__(16) float Ks[64][68];
  __shared__ __align__(16) float Vt[64][68];  // [dim][token]
  __shared__ __align__(16) float Ps[64][68];
  const int qt = blockIdx.x, h = blockIdx.y, b = blockIdx.z;
  const int t = threadIdx.x;
  const int tm = t >> 4, tn = t & 15;
  const float aw = 1.f / (1.f + __expf(-freqw[0]));
  const float iaw = 1.f - aw;
  const size_t base = ((size_t)b * H_ + h) * (size_t)(N_ * HD_);
#pragma unroll
  for (int rep = 0; rep < 4; ++rep) {
    int f = rep * 256 + t;
    int r = f >> 4, d4 = (f & 15) * 4;
    *(float4*)(&Qs[r][d4]) = *(const float4*)(qg + base + (size_t)(qt * 64 + r) * HD_ + d4);
  }
  float mrow[4], lrow[4], accO[4][4], cr[4];
#pragma unroll
  for (int i = 0; i < 4; ++i) {
    mrow[i] = -1e30f; lrow[i] = 0.f;
    cr[i] = crow[b * N_ + qt * 64 + tm * 4 + i];
#pragma unroll
    for (int j = 0; j < 4; ++j) accO[i][j] = 0.f;
  }
  for (int kt = 0; kt < 16; ++kt) {
    __syncthreads();
#pragma unroll
    for (int rep = 0; rep < 4; ++rep) {
      int f = rep * 256 + t;
      int r = f >> 4, d4 = (f & 15) * 4;
      const float4 k4 = *(const float4*)(kg + base + (size_t)(kt * 64 + r) * HD_ + d4);
      *(float4*)(&Ks[r][d4]) = k4;
      const float4 v4 = *(const float4*)(vg + base + (size_t)(kt * 64 + r) * HD_ + d4);
      Vt[d4 + 0][r] = v4.x; Vt[d4 + 1][r] = v4.y; Vt[d4 + 2][r] = v4.z; Vt[d4 + 3][r] = v4.w;
    }
    __syncthreads();
    float s[4][4] = {};
#pragma unroll 4
    for (int dd = 0; dd < 64; dd += 4) {
      float4 ra[4], rb[4];
#pragma unroll
      for (int i = 0; i < 4; ++i) ra[i] = *(const float4*)(&Qs[tm * 4 + i][dd]);
#pragma unroll
      for (int j = 0; j < 4; ++j) rb[j] = *(const float4*)(&Ks[tn + 16 * j][dd]);
#pragma unroll
      for (int i = 0; i < 4; ++i)
#pragma unroll
        for (int j = 0; j < 4; ++j)
          s[i][j] += ra[i].x * rb[j].x + ra[i].y * rb[j].y + ra[i].z * rb[j].z + ra[i].w * rb[j].w;
    }
    float dm[4];
#pragma unroll
    for (int j = 0; j < 4; ++j) dm[j] = dfeat[b * N_ + kt * 64 + tn + 16 * j];
#pragma unroll
    for (int i = 0; i < 4; ++i)
#pragma unroll
      for (int j = 0; j < 4; ++j) {
        float fv = fminf(fmaxf(cr[i] * dm[j], 0.f), 1.f);
        s[i][j] = iaw * s[i][j] + aw * fv;
      }
#pragma unroll
    for (int i = 0; i < 4; ++i) {
      float mt = fmaxf(fmaxf(s[i][0], s[i][1]), fmaxf(s[i][2], s[i][3]));
      mt = fmaxf(mt, __shfl_xor(mt, 1));
      mt = fmaxf(mt, __shfl_xor(mt, 2));
      mt = fmaxf(mt, __shfl_xor(mt, 4));
      mt = fmaxf(mt, __shfl_xor(mt, 8));
      float mnew = fmaxf(mrow[i], mt);
      float p[4], ts = 0.f;
#pragma unroll
      for (int j = 0; j < 4; ++j) { p[j] = __expf(s[i][j] - mnew); ts += p[j]; }
      ts += __shfl_xor(ts, 1);
      ts += __shfl_xor(ts, 2);
      ts += __shfl_xor(ts, 4);
      ts += __shfl_xor(ts, 8);
      float sc = __expf(mrow[i] - mnew);
      lrow[i] = lrow[i] * sc + ts;
      mrow[i] = mnew;
#pragma unroll
      for (int j = 0; j < 4; ++j) accO[i][j] *= sc;
#pragma unroll
      for (int j = 0; j < 4; ++j) Ps[tm * 4 + i][tn + 16 * j] = p[j];
    }
    __syncthreads();
#pragma unroll 4
    for (int kk = 0; kk < 64; kk += 4) {
      float4 rp[4], rv[4];
#pragma unroll
      for (int i = 0; i < 4; ++i) rp[i] = *(const float4*)(&Ps[tm * 4 + i][kk]);
#pragma unroll
      for (int j = 0; j < 4; ++j) rv[j] = *(const float4*)(&Vt[tn + 16 * j][kk]);
#pragma unroll
      for (int i = 0; i < 4; ++i)
#pragma unroll
        for (int j = 0; j < 4; ++j)
          accO[i][j] += rp[i].x * rv[j].x + rp[i].y * rv[j].y + rp[i].z * rv[j].z + rp[i].w * rv[j].w;
    }
  }
#pragma unroll
  for (int i = 0; i < 4; ++i) {
    int n = qt * 64 + tm * 4 + i;
    float inv = 1.f / lrow[i];
#pragma unroll
    for (int j = 0; j < 4; ++j)
      ao[((size_t)b * N_ + n) * DIM_ + h * HD_ + tn + 16 * j] = accO[i][j] * inv;
  }
}

// ---------- output projection: (16384x512)@(512x512)+b -> d_out ----------
__global__ __launch_bounds__(256) void k_proj(const float* __restrict__ a,
                                              const float* __restrict__ w,
                                              const float* __restrict__ bias,
                                              float* __restrict__ out) {
  __shared__ __align__(16) float As[16][68];
  __shared__ __align__(16) float Bs[16][68];
  const int t = threadIdx.x;
  const int row0 = blockIdx.y * 64;
  const int col0 = blockIdx.x * 64;
  const int tm = t >> 4, tn = t & 15;
  float acc[4][4] = {};
  for (int k0 = 0; k0 < DIM_; k0 += 16) {
    {
      int m = t >> 2;
      int kb = (t & 3) * 4;
      const float4 a4 = *(const float4*)(a + (size_t)(row0 + m) * DIM_ + k0 + kb);
      As[kb + 0][m] = a4.x; As[kb + 1][m] = a4.y; As[kb + 2][m] = a4.z; As[kb + 3][m] = a4.w;
    }
    {
      int kk = t >> 4;
      int nb = (t & 15) * 4;
      *(float4*)(&Bs[kk][nb]) = *(const float4*)(w + (size_t)(k0 + kk) * DIM_ + col0 + nb);
    }
    __syncthreads();
#pragma unroll
    for (int kk = 0; kk < 16; ++kk) {
      float4 ra = *(const float4*)(&As[kk][tm * 4]);
      float4 rb = *(const float4*)(&Bs[kk][tn * 4]);
      float av[4] = {ra.x, ra.y, ra.z, ra.w};
      float bv[4] = {rb.x, rb.y, rb.z, rb.w};
#pragma unroll
      for (int i = 0; i < 4; ++i)
#pragma unroll
        for (int j = 0; j < 4; ++j) acc[i][j] += av[i] * bv[j];
    }
    __syncthreads();
  }
  float bj[4];
#pragma unroll
  for (int j = 0; j < 4; ++j) bj[j] = bias[col0 + tn * 4 + j];
#pragma unroll
  for (int i = 0; i < 4; ++i) {
    int gm = row0 + tm * 4 + i;
    float4 o;
    o.x = acc[i][0] + bj[0];
    o.y = acc[i][1] + bj[1];
    o.z = acc[i][2] + bj[2];
    o.w = acc[i][3] + bj[3];
    *(float4*)(out + (size_t)gm * DIM_ + col0 + tn * 4) = o;
  }
}

extern "C" void kernel_launch(void* const* d_in, const int* in_sizes, int n_in,
                              void* d_out, int out_size, void* d_ws, size_t ws_size,
                              hipStream_t stream) {
  const float* x      = (const float*)d_in[0];
  const float* qkv_w  = (const float*)d_in[1];
  const float* qkv_b  = (const float*)d_in[2];
  const float* proj_w = (const float*)d_in[3];
  const float* proj_b = (const float*)d_in[4];
  const float* h1_w   = (const float*)d_in[5];
  const float* h1_b   = (const float*)d_in[6];
  const float* h2_w   = (const float*)d_in[7];
  const float* h2_b   = (const float*)d_in[8];
  const float* freq_w = (const float*)d_in[9];

  float* ws    = (float*)d_ws;
  float* q     = ws + OFF_Q;
  float* k     = ws + OFF_K;
  float* v     = ws + OFF_V;
  float* ao    = ws + OFF_AO;
  float* xmean = ws + OFF_XMEAN;
  float* xavg  = ws + OFF_XAVG;
  float* dfeat = ws + OFF_D;
  float* tsum  = ws + OFF_T;
  float* crow  = ws + OFF_C;
  float* out   = (float*)d_out;

  hipMemsetAsync(xavg, 0, (size_t)B_ * DIM_ * sizeof(float), stream);

  k_xmean<<<dim3(B_ * N_ / 4), 256, 0, stream>>>(x, xmean);
  k_xavg<<<dim3(B_, 16), 512, 0, stream>>>(x, xavg);
  k_dct<<<dim3(B_), 1024, 0, stream>>>(xmean, dfeat, tsum);
  k_headw<<<dim3(B_), 128, 0, stream>>>(xavg, h1_w, h1_b, h2_w, h2_b, dfeat, tsum, crow);
  k_qkv<<<dim3(1536 / 64, B_ * N_ / 64), 256, 0, stream>>>(x, qkv_w, qkv_b, q, k, v);
  k_attn<<<dim3(N_ / 64, H_, B_), 256, 0, stream>>>(q, k, v, crow, dfeat, freq_w, ao);
  k_proj<<<dim3(DIM_ / 64, B_ * N_ / 64), 256, 0, stream>>>(ao, proj_w, proj_b, out);
}

// Round 4
// 1063.464 us; speedup vs baseline: 1.3188x; 1.3188x over previous
//
#include <hip/hip_runtime.h>
#include <math.h>

#define PI_F 3.14159265358979323846f

typedef __attribute__((ext_vector_type(8))) short          bf16x8;
typedef __attribute__((ext_vector_type(8))) unsigned short ushort8;
typedef __attribute__((ext_vector_type(4))) float          f32x4;

__device__ __forceinline__ unsigned short f2bf(float f) {
  union { float f; unsigned u; } v; v.f = f;
  unsigned r = v.u + 0x7fffu + ((v.u >> 16) & 1u);
  return (unsigned short)(r >> 16);
}

// ---- workspace layout (byte offsets) ----
// XB (bf16 x) and AO (bf16 attn-out) share a region: disjoint lifetimes.
static const size_t OFF_XB  = 0;           // bf16 (16384,512) 16 MB  [= OFF_AO]
static const size_t OFF_QF  = 16777216;    // f32 q scaled (B,H,N,64) 33.5 MB
static const size_t OFF_KF  = 50331648;    // f32 k
static const size_t OFF_VF  = 83886080;    // f32 v
static const size_t OFF_WT  = 117440512;   // bf16 qkv_w^T (1536,512)
static const size_t OFF_PWT = 119013376;   // bf16 proj_w^T (512,512)
static const size_t OFF_XM  = 119537664;   // f32 xmean (B,N)
static const size_t OFF_XA  = 119603200;   // f32 xavg  (B,512)
static const size_t OFF_DF  = 119635968;   // f32 dfeat (B,N)
static const size_t OFF_TS  = 119701504;   // f32 tsum  (B)
static const size_t OFF_CR  = 119701568;   // f32 crow  (B,N)
// end ~119.77 MB < 128.2 MiB proven available in round 1

// ---------- x row-mean + f32->bf16 convert ----------
__global__ __launch_bounds__(256) void k_xmean_cvt(const float* __restrict__ x,
                                                   float* __restrict__ xmean,
                                                   unsigned short* __restrict__ xb) {
  int row  = blockIdx.x * 4 + (threadIdx.x >> 6);
  int lane = threadIdx.x & 63;
  const float* px = x + (size_t)row * 512 + lane * 8;
  float4 a = ((const float4*)px)[0];
  float4 b = ((const float4*)px)[1];
  ushort8 o;
  o[0] = f2bf(a.x); o[1] = f2bf(a.y); o[2] = f2bf(a.z); o[3] = f2bf(a.w);
  o[4] = f2bf(b.x); o[5] = f2bf(b.y); o[6] = f2bf(b.z); o[7] = f2bf(b.w);
  *(ushort8*)(xb + (size_t)row * 512 + lane * 8) = o;
  float s = a.x + a.y + a.z + a.w + b.x + b.y + b.z + b.w;
  for (int off = 32; off; off >>= 1) s += __shfl_down(s, off);
  if (lane == 0) xmean[row] = s * (1.f / 512.f);
}

// ---------- x column sums over N (partial, atomic) ----------
__global__ __launch_bounds__(512) void k_xavg(const float* __restrict__ x,
                                              float* __restrict__ xavg) {
  int b = blockIdx.x, chunk = blockIdx.y;
  int c = threadIdx.x;
  const float* px = x + ((size_t)b * 1024 + (size_t)chunk * 64) * 512 + c;
  float s = 0.f;
#pragma unroll 8
  for (int n = 0; n < 64; ++n) s += px[(size_t)n * 512];
  atomicAdd(&xavg[b * 512 + c], s);
}

// ---------- DCT feature ----------
__global__ __launch_bounds__(1024) void k_dct(const float* __restrict__ xmean,
                                              float* __restrict__ dfeat,
                                              float* __restrict__ tsum) {
  __shared__ float A[32][33], Dm[32][33], Tm[32][33];
  __shared__ float red[1024];
  __shared__ float nrm;
  int b = blockIdx.x, t = threadIdx.x;
  int kk = t >> 5, nn = t & 31;
  A[kk][nn] = xmean[b * 1024 + t];
  float dv = (kk == 0) ? sqrtf(1.f / 32.f)
                       : sqrtf(2.f / 32.f) * cosf(PI_F * (2.f * nn + 1.f) * (float)kk / 64.f);
  Dm[kk][nn] = dv;
  __syncthreads();
  float acc = 0.f;
  for (int m = 0; m < 32; ++m) acc += Dm[kk][m] * A[m][nn];
  Tm[kk][nn] = acc;
  __syncthreads();
  float acc2 = 0.f;
  for (int n = 0; n < 32; ++n) acc2 += Tm[kk][n] * Dm[nn][n];
  float val = fminf(fmaxf(acc2, -10.f), 10.f);
  red[t] = val * val;
  __syncthreads();
  for (int s = 512; s; s >>= 1) { if (t < s) red[t] += red[t + s]; __syncthreads(); }
  if (t == 0) nrm = sqrtf(red[0]) + 1e-5f;
  __syncthreads();
  float dn = val / nrm;
  dfeat[b * 1024 + t] = dn;
  red[t] = dn;
  __syncthreads();
  for (int s = 512; s; s >>= 1) { if (t < s) red[t] += red[t + s]; __syncthreads(); }
  if (t == 0) tsum[b] = red[0];
}

// ---------- head MLP -> row coefficients ----------
__global__ __launch_bounds__(128) void k_headw(const float* __restrict__ xavg,
                                               const float* __restrict__ h1w,
                                               const float* __restrict__ h1b,
                                               const float* __restrict__ h2w,
                                               const float* __restrict__ h2b,
                                               const float* __restrict__ dfeat,
                                               const float* __restrict__ tsum,
                                               float* __restrict__ crow) {
  __shared__ float xa[512];
  __shared__ float h1s[128];
  __shared__ float hw[8];
  int b = blockIdx.x, t = threadIdx.x;
  for (int i = t; i < 512; i += 128) xa[i] = xavg[b * 512 + i] * (1.f / 1024.f);
  __syncthreads();
  float acc = h1b[t];
  for (int c = 0; c < 512; ++c) acc += xa[c] * h1w[c * 128 + t];
  h1s[t] = fmaxf(acc, 0.f);
  __syncthreads();
  if (t < 8) {
    float a2 = h2b[t];
    for (int j = 0; j < 128; ++j) a2 += h1s[j] * h2w[j * 8 + t];
    hw[t] = a2;
  }
  __syncthreads();
  float s = 0.f;
#pragma unroll
  for (int h = 0; h < 8; ++h) s += hw[h] * hw[h];
  float Tb = tsum[b];
  for (int n = t; n < 1024; n += 128) {
    float dn = dfeat[b * 1024 + n];
    float p = s * dn;
    crow[b * 1024 + n] = p / fmaxf(p * Tb, 1e-5f);
  }
}

// ---------- weight transpose+convert: w (K,Nw) f32 -> wt (Nw,512) bf16 ----------
__global__ __launch_bounds__(256) void k_wtrans(const float* __restrict__ w,
                                                unsigned short* __restrict__ wt,
                                                int Nw) {
  __shared__ unsigned short T[64 * 65];
  int n0 = blockIdx.x * 64, k0 = blockIdx.y * 64;
  int t = threadIdx.x;
  int r = t >> 2, c0 = (t & 3) * 16;
  const float* src = w + (size_t)(k0 + r) * Nw + n0 + c0;
#pragma unroll
  for (int q = 0; q < 4; ++q) {
    float4 v4 = *(const float4*)(src + q * 4);
    T[(c0 + q * 4 + 0) * 65 + r] = f2bf(v4.x);
    T[(c0 + q * 4 + 1) * 65 + r] = f2bf(v4.y);
    T[(c0 + q * 4 + 2) * 65 + r] = f2bf(v4.z);
    T[(c0 + q * 4 + 3) * 65 + r] = f2bf(v4.w);
  }
  __syncthreads();
  int nl = t >> 2, koff = (t & 3) * 16;
  ushort8 o0, o1;
#pragma unroll
  for (int e = 0; e < 8; ++e) o0[e] = T[nl * 65 + koff + e];
#pragma unroll
  for (int e = 0; e < 8; ++e) o1[e] = T[nl * 65 + koff + 8 + e];
  unsigned short* dst = wt + (size_t)(n0 + nl) * 512 + k0 + koff;
  *(ushort8*)(dst) = o0;
  *(ushort8*)(dst + 8) = o1;
}

// ---------- bf16 MFMA GEMM 128x128, BK=64; QKV epilogue -> f32 q/k/v ----------
__global__ __launch_bounds__(256) void k_gemm_qkv(const unsigned short* __restrict__ A,
                                                  const unsigned short* __restrict__ Bt,
                                                  const float* __restrict__ bias,
                                                  float* __restrict__ o_q,
                                                  float* __restrict__ o_k,
                                                  float* __restrict__ o_v) {
  __shared__ __align__(16) unsigned short As[128 * 72];
  __shared__ __align__(16) unsigned short Bs[128 * 72];
  const int t = threadIdx.x, w = t >> 6, l = t & 63;
  const int lg = l >> 4, ln = l & 15;
  const int wm = w >> 1, wn = w & 1;
  const int row0 = blockIdx.y * 128, col0 = blockIdx.x * 128;

  f32x4 acc[4][4];
#pragma unroll
  for (int i = 0; i < 4; ++i)
#pragma unroll
    for (int j = 0; j < 4; ++j) acc[i][j] = (f32x4){0.f, 0.f, 0.f, 0.f};

  int aoff[4][2], boff[4][2];
#pragma unroll
  for (int mt = 0; mt < 4; ++mt)
#pragma unroll
    for (int ks = 0; ks < 2; ++ks) {
      aoff[mt][ks] = (wm * 64 + mt * 16 + ln) * 72 + (lg + ks * 4) * 8;
      boff[mt][ks] = (wn * 64 + mt * 16 + ln) * 72 + (lg + ks * 4) * 8;
    }

  for (int k0 = 0; k0 < 512; k0 += 64) {
#pragma unroll
    for (int it = 0; it < 4; ++it) {
      int idx = it * 256 + t;
      int row = idx >> 3, c0 = (idx & 7) * 8;
      *(ushort8*)(&As[row * 72 + c0]) =
          *(const ushort8*)(A + (size_t)(row0 + row) * 512 + k0 + c0);
      *(ushort8*)(&Bs[row * 72 + c0]) =
          *(const ushort8*)(Bt + (size_t)(col0 + row) * 512 + k0 + c0);
    }
    __syncthreads();
#pragma unroll
    for (int ks = 0; ks < 2; ++ks) {
      bf16x8 av[4], bv[4];
#pragma unroll
      for (int mt = 0; mt < 4; ++mt) av[mt] = *(const bf16x8*)(As + aoff[mt][ks]);
#pragma unroll
      for (int nt = 0; nt < 4; ++nt) bv[nt] = *(const bf16x8*)(Bs + boff[nt][ks]);
#pragma unroll
      for (int mt = 0; mt < 4; ++mt)
#pragma unroll
        for (int nt = 0; nt < 4; ++nt)
          acc[mt][nt] = __builtin_amdgcn_mfma_f32_16x16x32_bf16(av[mt], bv[nt], acc[mt][nt], 0, 0, 0);
    }
    __syncthreads();
  }

  const int sel = col0 >> 9;
  float* outp = (sel == 0) ? o_q : (sel == 1) ? o_k : o_v;
  const float scl = (sel == 0) ? 0.125f : 1.f;
#pragma unroll
  for (int nt = 0; nt < 4; ++nt) {
    int colg = col0 + wn * 64 + nt * 16 + ln;
    float bcol = bias[colg];
    int h = (colg >> 6) & 7, d = colg & 63;
#pragma unroll
    for (int mt = 0; mt < 4; ++mt)
#pragma unroll
      for (int r = 0; r < 4; ++r) {
        int row = row0 + wm * 64 + mt * 16 + lg * 4 + r;
        int bidx = row >> 10, n = row & 1023;
        outp[(((size_t)(bidx * 8 + h)) << 16) + (n << 6) + d] = (acc[mt][nt][r] + bcol) * scl;
      }
  }
}

// ---------- bf16 MFMA GEMM 128x128; proj epilogue -> f32 out ----------
__global__ __launch_bounds__(256) void k_gemm_proj(const unsigned short* __restrict__ A,
                                                   const unsigned short* __restrict__ Bt,
                                                   const float* __restrict__ bias,
                                                   float* __restrict__ o_f) {
  __shared__ __align__(16) unsigned short As[128 * 72];
  __shared__ __align__(16) unsigned short Bs[128 * 72];
  const int t = threadIdx.x, w = t >> 6, l = t & 63;
  const int lg = l >> 4, ln = l & 15;
  const int wm = w >> 1, wn = w & 1;
  const int row0 = blockIdx.y * 128, col0 = blockIdx.x * 128;

  f32x4 acc[4][4];
#pragma unroll
  for (int i = 0; i < 4; ++i)
#pragma unroll
    for (int j = 0; j < 4; ++j) acc[i][j] = (f32x4){0.f, 0.f, 0.f, 0.f};

  int aoff[4][2], boff[4][2];
#pragma unroll
  for (int mt = 0; mt < 4; ++mt)
#pragma unroll
    for (int ks = 0; ks < 2; ++ks) {
      aoff[mt][ks] = (wm * 64 + mt * 16 + ln) * 72 + (lg + ks * 4) * 8;
      boff[mt][ks] = (wn * 64 + mt * 16 + ln) * 72 + (lg + ks * 4) * 8;
    }

  for (int k0 = 0; k0 < 512; k0 += 64) {
#pragma unroll
    for (int it = 0; it < 4; ++it) {
      int idx = it * 256 + t;
      int row = idx >> 3, c0 = (idx & 7) * 8;
      *(ushort8*)(&As[row * 72 + c0]) =
          *(const ushort8*)(A + (size_t)(row0 + row) * 512 + k0 + c0);
      *(ushort8*)(&Bs[row * 72 + c0]) =
          *(const ushort8*)(Bt + (size_t)(col0 + row) * 512 + k0 + c0);
    }
    __syncthreads();
#pragma unroll
    for (int ks = 0; ks < 2; ++ks) {
      bf16x8 av[4], bv[4];
#pragma unroll
      for (int mt = 0; mt < 4; ++mt) av[mt] = *(const bf16x8*)(As + aoff[mt][ks]);
#pragma unroll
      for (int nt = 0; nt < 4; ++nt) bv[nt] = *(const bf16x8*)(Bs + boff[nt][ks]);
#pragma unroll
      for (int mt = 0; mt < 4; ++mt)
#pragma unroll
        for (int nt = 0; nt < 4; ++nt)
          acc[mt][nt] = __builtin_amdgcn_mfma_f32_16x16x32_bf16(av[mt], bv[nt], acc[mt][nt], 0, 0, 0);
    }
    __syncthreads();
  }

#pragma unroll
  for (int nt = 0; nt < 4; ++nt) {
    int colg = col0 + wn * 64 + nt * 16 + ln;
    float bcol = bias[colg];
#pragma unroll
    for (int mt = 0; mt < 4; ++mt)
#pragma unroll
      for (int r = 0; r < 4; ++r) {
        int row = row0 + wm * 64 + mt * 16 + lg * 4 + r;
        o_f[(size_t)row * 512 + colg] = acc[mt][nt][r] + bcol;
      }
  }
}

// ---------- round-1 f32 flash attention (known good), bf16 ao output ----------
__global__ __launch_bounds__(256) void k_attn(const float* __restrict__ qg,
                                              const float* __restrict__ kg,
                                              const float* __restrict__ vg,
                                              const float* __restrict__ crow,
                                              const float* __restrict__ dfeat,
                                              const float* __restrict__ freqw,
                                              unsigned short* __restrict__ ao) {
  __shared__ __align__(16) float Qs[64][68];
  __shared__ __align__(16) float Ks[64][68];
  __shared__ __align__(16) float Vt[64][68];
  __shared__ __align__(16) float Ps[64][68];
  const int qt = blockIdx.x, h = blockIdx.y, b = blockIdx.z;
  const int t = threadIdx.x;
  const int tm = t >> 4, tn = t & 15;
  const float aw = 1.f / (1.f + __expf(-freqw[0]));
  const float iaw = 1.f - aw;
  const size_t base = ((size_t)b * 8 + h) * (size_t)(1024 * 64);
#pragma unroll
  for (int rep = 0; rep < 4; ++rep) {
    int f = rep * 256 + t;
    int r = f >> 4, d4 = (f & 15) * 4;
    *(float4*)(&Qs[r][d4]) = *(const float4*)(qg + base + (size_t)(qt * 64 + r) * 64 + d4);
  }
  float mrow[4], lrow[4], accO[4][4], cr[4];
#pragma unroll
  for (int i = 0; i < 4; ++i) {
    mrow[i] = -1e30f; lrow[i] = 0.f;
    cr[i] = crow[b * 1024 + qt * 64 + tm * 4 + i];
#pragma unroll
    for (int j = 0; j < 4; ++j) accO[i][j] = 0.f;
  }
  for (int kt = 0; kt < 16; ++kt) {
    __syncthreads();
#pragma unroll
    for (int rep = 0; rep < 4; ++rep) {
      int f = rep * 256 + t;
      int r = f >> 4, d4 = (f & 15) * 4;
      const float4 k4 = *(const float4*)(kg + base + (size_t)(kt * 64 + r) * 64 + d4);
      *(float4*)(&Ks[r][d4]) = k4;
      const float4 v4 = *(const float4*)(vg + base + (size_t)(kt * 64 + r) * 64 + d4);
      Vt[d4 + 0][r] = v4.x; Vt[d4 + 1][r] = v4.y; Vt[d4 + 2][r] = v4.z; Vt[d4 + 3][r] = v4.w;
    }
    __syncthreads();
    float s[4][4] = {};
#pragma unroll 4
    for (int dd = 0; dd < 64; dd += 4) {
      float4 ra[4], rb[4];
#pragma unroll
      for (int i = 0; i < 4; ++i) ra[i] = *(const float4*)(&Qs[tm * 4 + i][dd]);
#pragma unroll
      for (int j = 0; j < 4; ++j) rb[j] = *(const float4*)(&Ks[tn + 16 * j][dd]);
#pragma unroll
      for (int i = 0; i < 4; ++i)
#pragma unroll
        for (int j = 0; j < 4; ++j)
          s[i][j] += ra[i].x * rb[j].x + ra[i].y * rb[j].y + ra[i].z * rb[j].z + ra[i].w * rb[j].w;
    }
    float dm[4];
#pragma unroll
    for (int j = 0; j < 4; ++j) dm[j] = dfeat[b * 1024 + kt * 64 + tn + 16 * j];
#pragma unroll
    for (int i = 0; i < 4; ++i)
#pragma unroll
      for (int j = 0; j < 4; ++j) {
        float fv = fminf(fmaxf(cr[i] * dm[j], 0.f), 1.f);
        s[i][j] = iaw * s[i][j] + aw * fv;
      }
#pragma unroll
    for (int i = 0; i < 4; ++i) {
      float mt_ = fmaxf(fmaxf(s[i][0], s[i][1]), fmaxf(s[i][2], s[i][3]));
      mt_ = fmaxf(mt_, __shfl_xor(mt_, 1));
      mt_ = fmaxf(mt_, __shfl_xor(mt_, 2));
      mt_ = fmaxf(mt_, __shfl_xor(mt_, 4));
      mt_ = fmaxf(mt_, __shfl_xor(mt_, 8));
      float mnew = fmaxf(mrow[i], mt_);
      float p[4], ts = 0.f;
#pragma unroll
      for (int j = 0; j < 4; ++j) { p[j] = __expf(s[i][j] - mnew); ts += p[j]; }
      ts += __shfl_xor(ts, 1);
      ts += __shfl_xor(ts, 2);
      ts += __shfl_xor(ts, 4);
      ts += __shfl_xor(ts, 8);
      float sc = __expf(mrow[i] - mnew);
      lrow[i] = lrow[i] * sc + ts;
      mrow[i] = mnew;
#pragma unroll
      for (int j = 0; j < 4; ++j) accO[i][j] *= sc;
#pragma unroll
      for (int j = 0; j < 4; ++j) Ps[tm * 4 + i][tn + 16 * j] = p[j];
    }
    __syncthreads();
#pragma unroll 4
    for (int kk = 0; kk < 64; kk += 4) {
      float4 rp[4], rv[4];
#pragma unroll
      for (int i = 0; i < 4; ++i) rp[i] = *(const float4*)(&Ps[tm * 4 + i][kk]);
#pragma unroll
      for (int j = 0; j < 4; ++j) rv[j] = *(const float4*)(&Vt[tn + 16 * j][kk]);
#pragma unroll
      for (int i = 0; i < 4; ++i)
#pragma unroll
        for (int j = 0; j < 4; ++j)
          accO[i][j] += rp[i].x * rv[j].x + rp[i].y * rv[j].y + rp[i].z * rv[j].z + rp[i].w * rv[j].w;
    }
  }
#pragma unroll
  for (int i = 0; i < 4; ++i) {
    int n = qt * 64 + tm * 4 + i;
    float inv = 1.f / lrow[i];
#pragma unroll
    for (int j = 0; j < 4; ++j)
      ao[((size_t)b * 1024 + n) * 512 + h * 64 + tn + 16 * j] = f2bf(accO[i][j] * inv);
  }
}

extern "C" void kernel_launch(void* const* d_in, const int* in_sizes, int n_in,
                              void* d_out, int out_size, void* d_ws, size_t ws_size,
                              hipStream_t stream) {
  const float* x      = (const float*)d_in[0];
  const float* qkv_w  = (const float*)d_in[1];
  const float* qkv_b  = (const float*)d_in[2];
  const float* proj_w = (const float*)d_in[3];
  const float* proj_b = (const float*)d_in[4];
  const float* h1_w   = (const float*)d_in[5];
  const float* h1_b   = (const float*)d_in[6];
  const float* h2_w   = (const float*)d_in[7];
  const float* h2_b   = (const float*)d_in[8];
  const float* freq_w = (const float*)d_in[9];

  char* ws = (char*)d_ws;
  unsigned short* xb  = (unsigned short*)(ws + OFF_XB);
  unsigned short* ao  = (unsigned short*)(ws + OFF_XB);  // aliased, disjoint lifetime
  float* qf   = (float*)(ws + OFF_QF);
  float* kf   = (float*)(ws + OFF_KF);
  float* vf   = (float*)(ws + OFF_VF);
  unsigned short* wt  = (unsigned short*)(ws + OFF_WT);
  unsigned short* pwt = (unsigned short*)(ws + OFF_PWT);
  float* xmean = (float*)(ws + OFF_XM);
  float* xavg  = (float*)(ws + OFF_XA);
  float* dfeat = (float*)(ws + OFF_DF);
  float* tsum  = (float*)(ws + OFF_TS);
  float* crow  = (float*)(ws + OFF_CR);
  float* out   = (float*)d_out;

  hipMemsetAsync(xavg, 0, 16 * 512 * sizeof(float), stream);

  k_xmean_cvt<<<dim3(4096), 256, 0, stream>>>(x, xmean, xb);
  k_xavg<<<dim3(16, 16), 512, 0, stream>>>(x, xavg);
  k_dct<<<dim3(16), 1024, 0, stream>>>(xmean, dfeat, tsum);
  k_headw<<<dim3(16), 128, 0, stream>>>(xavg, h1_w, h1_b, h2_w, h2_b, dfeat, tsum, crow);
  k_wtrans<<<dim3(24, 8), 256, 0, stream>>>(qkv_w, wt, 1536);
  k_wtrans<<<dim3(8, 8), 256, 0, stream>>>(proj_w, pwt, 512);
  k_gemm_qkv<<<dim3(12, 128), 256, 0, stream>>>(xb, wt, qkv_b, qf, kf, vf);
  k_attn<<<dim3(16, 8, 16), 256, 0, stream>>>(qf, kf, vf, crow, dfeat, freq_w, ao);
  k_gemm_proj<<<dim3(4, 128), 256, 0, stream>>>(ao, pwt, proj_b, out);
}

// Round 5
// 237.626 us; speedup vs baseline: 5.9023x; 4.4754x over previous
//
#include <hip/hip_runtime.h>
#include <math.h>

#define PI_F 3.14159265358979323846f

typedef __attribute__((ext_vector_type(8))) short          bf16x8;
typedef __attribute__((ext_vector_type(8))) unsigned short ushort8;
typedef __attribute__((ext_vector_type(4))) float          f32x4;

__device__ __forceinline__ unsigned short f2bf(float f) {
  union { float f; unsigned u; } v; v.f = f;
  unsigned r = v.u + 0x7fffu + ((v.u >> 16) & 1u);
  return (unsigned short)(r >> 16);
}

// ---- workspace layout (BYTE offsets; bf16 tensors are 2 B/elem!) ----
// Round-2/3 bug: these offsets were element counts -> Q/K/V/VT/AO overlapped.
static const size_t OFF_XB  = 0;           // bf16 x      (16384,512)   16 MB [0,16M)
static const size_t OFF_QB  = 16777216;    // bf16 q*SCL  (B,H,N,64)    16 MB [16M,32M)
static const size_t OFF_KB  = 33554432;    // bf16 k                    16 MB [32M,48M)
static const size_t OFF_VB  = 50331648;    // bf16 v                    16 MB [48M,64M)
static const size_t OFF_VT  = 67108864;    // bf16 v^T    (B,H,64,N)    16 MB [64M,80M)
static const size_t OFF_AO  = 83886080;    // bf16 attn out (16384,512) 16 MB [80M,96M)
static const size_t OFF_WT  = 100663296;   // bf16 qkv_w^T (1536,512)  1.5 MB
static const size_t OFF_PWT = 102236160;   // bf16 proj_w^T (512,512)  0.5 MB
static const size_t OFF_XM  = 102760448;   // f32 xmean (B,N)
static const size_t OFF_XA  = 102825984;   // f32 xavg  (B,512)
static const size_t OFF_DF  = 102858752;   // f32 dfeat (B,N)
static const size_t OFF_TS  = 102924288;   // f32 tsum  (B)
static const size_t OFF_CR  = 102924352;   // f32 crow  (B,N)
// end 102989888 B ~= 98.2 MiB < 119.8 MB proven available in round 4

// ---------- x row-mean + f32->bf16 convert ----------
__global__ __launch_bounds__(256) void k_xmean_cvt(const float* __restrict__ x,
                                                   float* __restrict__ xmean,
                                                   unsigned short* __restrict__ xb) {
  int row  = blockIdx.x * 4 + (threadIdx.x >> 6);
  int lane = threadIdx.x & 63;
  const float* px = x + (size_t)row * 512 + lane * 8;
  float4 a = ((const float4*)px)[0];
  float4 b = ((const float4*)px)[1];
  ushort8 o;
  o[0] = f2bf(a.x); o[1] = f2bf(a.y); o[2] = f2bf(a.z); o[3] = f2bf(a.w);
  o[4] = f2bf(b.x); o[5] = f2bf(b.y); o[6] = f2bf(b.z); o[7] = f2bf(b.w);
  *(ushort8*)(xb + (size_t)row * 512 + lane * 8) = o;
  float s = a.x + a.y + a.z + a.w + b.x + b.y + b.z + b.w;
  for (int off = 32; off; off >>= 1) s += __shfl_down(s, off);
  if (lane == 0) xmean[row] = s * (1.f / 512.f);
}

// ---------- x column sums over N (partial, atomic) ----------
__global__ __launch_bounds__(512) void k_xavg(const float* __restrict__ x,
                                              float* __restrict__ xavg) {
  int b = blockIdx.x, chunk = blockIdx.y;
  int c = threadIdx.x;
  const float* px = x + ((size_t)b * 1024 + (size_t)chunk * 64) * 512 + c;
  float s = 0.f;
#pragma unroll 8
  for (int n = 0; n < 64; ++n) s += px[(size_t)n * 512];
  atomicAdd(&xavg[b * 512 + c], s);
}

// ---------- DCT feature ----------
__global__ __launch_bounds__(1024) void k_dct(const float* __restrict__ xmean,
                                              float* __restrict__ dfeat,
                                              float* __restrict__ tsum) {
  __shared__ float A[32][33], Dm[32][33], Tm[32][33];
  __shared__ float red[1024];
  __shared__ float nrm;
  int b = blockIdx.x, t = threadIdx.x;
  int kk = t >> 5, nn = t & 31;
  A[kk][nn] = xmean[b * 1024 + t];
  float dv = (kk == 0) ? sqrtf(1.f / 32.f)
                       : sqrtf(2.f / 32.f) * cosf(PI_F * (2.f * nn + 1.f) * (float)kk / 64.f);
  Dm[kk][nn] = dv;
  __syncthreads();
  float acc = 0.f;
  for (int m = 0; m < 32; ++m) acc += Dm[kk][m] * A[m][nn];
  Tm[kk][nn] = acc;
  __syncthreads();
  float acc2 = 0.f;
  for (int n = 0; n < 32; ++n) acc2 += Tm[kk][n] * Dm[nn][n];
  float val = fminf(fmaxf(acc2, -10.f), 10.f);
  red[t] = val * val;
  __syncthreads();
  for (int s = 512; s; s >>= 1) { if (t < s) red[t] += red[t + s]; __syncthreads(); }
  if (t == 0) nrm = sqrtf(red[0]) + 1e-5f;
  __syncthreads();
  float dn = val / nrm;
  dfeat[b * 1024 + t] = dn;
  red[t] = dn;
  __syncthreads();
  for (int s = 512; s; s >>= 1) { if (t < s) red[t] += red[t + s]; __syncthreads(); }
  if (t == 0) tsum[b] = red[0];
}

// ---------- head MLP -> row coefficients ----------
__global__ __launch_bounds__(128) void k_headw(const float* __restrict__ xavg,
                                               const float* __restrict__ h1w,
                                               const float* __restrict__ h1b,
                                               const float* __restrict__ h2w,
                                               const float* __restrict__ h2b,
                                               const float* __restrict__ dfeat,
                                               const float* __restrict__ tsum,
                                               float* __restrict__ crow) {
  __shared__ float xa[512];
  __shared__ float h1s[128];
  __shared__ float hw[8];
  int b = blockIdx.x, t = threadIdx.x;
  for (int i = t; i < 512; i += 128) xa[i] = xavg[b * 512 + i] * (1.f / 1024.f);
  __syncthreads();
  float acc = h1b[t];
  for (int c = 0; c < 512; ++c) acc += xa[c] * h1w[c * 128 + t];
  h1s[t] = fmaxf(acc, 0.f);
  __syncthreads();
  if (t < 8) {
    float a2 = h2b[t];
    for (int j = 0; j < 128; ++j) a2 += h1s[j] * h2w[j * 8 + t];
    hw[t] = a2;
  }
  __syncthreads();
  float s = 0.f;
#pragma unroll
  for (int h = 0; h < 8; ++h) s += hw[h] * hw[h];
  float Tb = tsum[b];
  for (int n = t; n < 1024; n += 128) {
    float dn = dfeat[b * 1024 + n];
    float p = s * dn;
    crow[b * 1024 + n] = p / fmaxf(p * Tb, 1e-5f);
  }
}

// ---------- weight transpose+convert: w (K,Nw) f32 -> wt (Nw,512) bf16 ----------
__global__ __launch_bounds__(256) void k_wtrans(const float* __restrict__ w,
                                                unsigned short* __restrict__ wt,
                                                int Nw) {
  __shared__ unsigned short T[64 * 65];
  int n0 = blockIdx.x * 64, k0 = blockIdx.y * 64;
  int t = threadIdx.x;
  int r = t >> 2, c0 = (t & 3) * 16;
  const float* src = w + (size_t)(k0 + r) * Nw + n0 + c0;
#pragma unroll
  for (int q = 0; q < 4; ++q) {
    float4 v4 = *(const float4*)(src + q * 4);
    T[(c0 + q * 4 + 0) * 65 + r] = f2bf(v4.x);
    T[(c0 + q * 4 + 1) * 65 + r] = f2bf(v4.y);
    T[(c0 + q * 4 + 2) * 65 + r] = f2bf(v4.z);
    T[(c0 + q * 4 + 3) * 65 + r] = f2bf(v4.w);
  }
  __syncthreads();
  int nl = t >> 2, koff = (t & 3) * 16;
  ushort8 o0, o1;
#pragma unroll
  for (int e = 0; e < 8; ++e) o0[e] = T[nl * 65 + koff + e];
#pragma unroll
  for (int e = 0; e < 8; ++e) o1[e] = T[nl * 65 + koff + 8 + e];
  unsigned short* dst = wt + (size_t)(n0 + nl) * 512 + k0 + koff;
  *(ushort8*)(dst) = o0;
  *(ushort8*)(dst + 8) = o1;
}

// ---------- V transpose: vb (B,H,N,64) -> vtg (B,H,64,N) bf16 ----------
__global__ __launch_bounds__(256) void k_vtrans(const unsigned short* __restrict__ vb,
                                                unsigned short* __restrict__ vtg) {
  __shared__ unsigned short T[64 * 65];
  int nt = blockIdx.x, h = blockIdx.y, b = blockIdx.z;
  size_t plane = ((size_t)(b * 8 + h)) << 16;
  int t = threadIdx.x;
  int r = t >> 2, c0 = (t & 3) * 16;
  const unsigned short* src = vb + plane + (size_t)(nt * 64 + r) * 64 + c0;
  ushort8 v0 = *(const ushort8*)(src);
  ushort8 v1 = *(const ushort8*)(src + 8);
#pragma unroll
  for (int e = 0; e < 8; ++e) T[(c0 + e) * 65 + r] = v0[e];
#pragma unroll
  for (int e = 0; e < 8; ++e) T[(c0 + 8 + e) * 65 + r] = v1[e];
  __syncthreads();
  int d = t >> 2, koff = (t & 3) * 16;
  ushort8 o0, o1;
#pragma unroll
  for (int e = 0; e < 8; ++e) o0[e] = T[d * 65 + koff + e];
#pragma unroll
  for (int e = 0; e < 8; ++e) o1[e] = T[d * 65 + koff + 8 + e];
  unsigned short* dst = vtg + plane + (size_t)d * 1024 + nt * 64 + koff;
  *(ushort8*)(dst) = o0;
  *(ushort8*)(dst + 8) = o1;
}

// ---------- bf16 MFMA GEMM, 128x128 tile, BK=64, reg-staged linear LDS ----------
// (verified in round 4) MODE 0: QKV epilogue -> bf16 q/k/v; MODE 1: proj -> f32
template <int MODE>
__global__ __launch_bounds__(256) void k_gemm(const unsigned short* __restrict__ A,
                                              const unsigned short* __restrict__ Bt,
                                              const float* __restrict__ bias,
                                              unsigned short* __restrict__ o_q,
                                              unsigned short* __restrict__ o_k,
                                              unsigned short* __restrict__ o_v,
                                              float* __restrict__ o_f) {
  __shared__ __align__(16) unsigned short As[128 * 72];
  __shared__ __align__(16) unsigned short Bs[128 * 72];
  const int t = threadIdx.x, w = t >> 6, l = t & 63;
  const int lg = l >> 4, ln = l & 15;
  const int wm = w >> 1, wn = w & 1;
  const int row0 = blockIdx.y * 128, col0 = blockIdx.x * 128;

  f32x4 acc[4][4];
#pragma unroll
  for (int i = 0; i < 4; ++i)
#pragma unroll
    for (int j = 0; j < 4; ++j) acc[i][j] = (f32x4){0.f, 0.f, 0.f, 0.f};

  int aoff[4][2], boff[4][2];
#pragma unroll
  for (int mt = 0; mt < 4; ++mt)
#pragma unroll
    for (int ks = 0; ks < 2; ++ks) {
      aoff[mt][ks] = (wm * 64 + mt * 16 + ln) * 72 + (lg + ks * 4) * 8;
      boff[mt][ks] = (wn * 64 + mt * 16 + ln) * 72 + (lg + ks * 4) * 8;
    }

  for (int k0 = 0; k0 < 512; k0 += 64) {
#pragma unroll
    for (int it = 0; it < 4; ++it) {
      int idx = it * 256 + t;
      int row = idx >> 3, c0 = (idx & 7) * 8;
      *(ushort8*)(&As[row * 72 + c0]) =
          *(const ushort8*)(A + (size_t)(row0 + row) * 512 + k0 + c0);
      *(ushort8*)(&Bs[row * 72 + c0]) =
          *(const ushort8*)(Bt + (size_t)(col0 + row) * 512 + k0 + c0);
    }
    __syncthreads();
#pragma unroll
    for (int ks = 0; ks < 2; ++ks) {
      bf16x8 av[4], bv[4];
#pragma unroll
      for (int mt = 0; mt < 4; ++mt) av[mt] = *(const bf16x8*)(As + aoff[mt][ks]);
#pragma unroll
      for (int nt = 0; nt < 4; ++nt) bv[nt] = *(const bf16x8*)(Bs + boff[nt][ks]);
#pragma unroll
      for (int mt = 0; mt < 4; ++mt)
#pragma unroll
        for (int nt = 0; nt < 4; ++nt)
          acc[mt][nt] = __builtin_amdgcn_mfma_f32_16x16x32_bf16(av[mt], bv[nt], acc[mt][nt], 0, 0, 0);
    }
    __syncthreads();
  }

  if (MODE == 0) {
    const int sel = col0 >> 9;
    unsigned short* outp = (sel == 0) ? o_q : (sel == 1) ? o_k : o_v;
    const float scl = (sel == 0) ? 0.125f : 1.f;
#pragma unroll
    for (int nt = 0; nt < 4; ++nt) {
      int colg = col0 + wn * 64 + nt * 16 + ln;
      float bcol = bias[colg];
      int h = (colg >> 6) & 7, d = colg & 63;
#pragma unroll
      for (int mt = 0; mt < 4; ++mt)
#pragma unroll
        for (int r = 0; r < 4; ++r) {
          int row = row0 + wm * 64 + mt * 16 + lg * 4 + r;
          int bidx = row >> 10, n = row & 1023;
          float val = (acc[mt][nt][r] + bcol) * scl;
          outp[(((size_t)(bidx * 8 + h)) << 16) + (n << 6) + d] = f2bf(val);
        }
    }
  } else {
#pragma unroll
    for (int nt = 0; nt < 4; ++nt) {
      int colg = col0 + wn * 64 + nt * 16 + ln;
      float bcol = bias[colg];
#pragma unroll
      for (int mt = 0; mt < 4; ++mt)
#pragma unroll
        for (int r = 0; r < 4; ++r) {
          int row = row0 + wm * 64 + mt * 16 + lg * 4 + r;
          o_f[(size_t)row * 512 + colg] = acc[mt][nt][r] + bcol;
        }
    }
  }
}

// ---------- flash attention, bf16 MFMA, rank-1 freq bias (reg-staged LDS) ----------
__global__ __launch_bounds__(256) void k_attn(const unsigned short* __restrict__ qb,
                                              const unsigned short* __restrict__ kb,
                                              const unsigned short* __restrict__ vtg,
                                              const float* __restrict__ crow,
                                              const float* __restrict__ dfeat,
                                              const float* __restrict__ freqw,
                                              unsigned short* __restrict__ ao) {
  __shared__ __align__(16) unsigned short Ks[64 * 72];
  __shared__ __align__(16) unsigned short Vs[64 * 72];
  __shared__ __align__(16) unsigned short Ps[4][16 * 72];
  const int qt = blockIdx.x, h = blockIdx.y, b = blockIdx.z;
  const int t = threadIdx.x, w = t >> 6, l = t & 63;
  const int lg = l >> 4, ln = l & 15;
  const size_t base = ((size_t)(b * 8 + h)) << 16;
  const float fw = freqw[0];
  const float aw = 1.f / (1.f + __expf(-fw));
  const float iaw = 1.f - aw;

  // Q fragments in registers (A-operand: m = ln, k-block = lg)
  const int qrow = qt * 64 + w * 16 + ln;
  bf16x8 qf0 = *(const bf16x8*)(qb + base + (size_t)qrow * 64 + lg * 8);
  bf16x8 qf1 = *(const bf16x8*)(qb + base + (size_t)qrow * 64 + lg * 8 + 32);

  float cr[4];
#pragma unroll
  for (int r = 0; r < 4; ++r) cr[r] = crow[b * 1024 + qt * 64 + w * 16 + lg * 4 + r];

  f32x4 accO[4];
#pragma unroll
  for (int dt = 0; dt < 4; ++dt) accO[dt] = (f32x4){0.f, 0.f, 0.f, 0.f};
  float mrow[4] = {-1e30f, -1e30f, -1e30f, -1e30f};
  float lrow[4] = {0.f, 0.f, 0.f, 0.f};

  // fragment read offsets: row ln, k-slots lg / lg+4 (linear, stride 72)
  int rdoff[2];
#pragma unroll
  for (int ks = 0; ks < 2; ++ks) rdoff[ks] = ln * 72 + (lg + ks * 4) * 8;

  for (int kt = 0; kt < 16; ++kt) {
    __syncthreads();  // previous tile fully consumed
#pragma unroll
    for (int it = 0; it < 2; ++it) {
      int idx = it * 256 + t;  // 0..511
      int row = idx >> 3, c0 = (idx & 7) * 8;
      ushort8 k8 = *(const ushort8*)(kb + base + (size_t)(kt * 64 + row) * 64 + c0);
      *(ushort8*)(&Ks[row * 72 + c0]) = k8;
      ushort8 v8 = *(const ushort8*)(vtg + base + (size_t)row * 1024 + kt * 64 + c0);
      *(ushort8*)(&Vs[row * 72 + c0]) = v8;
    }
    __syncthreads();

    // QK^T: S[q][key], 4 col-tiles x 2 K-steps
    f32x4 s[4];
#pragma unroll
    for (int nt = 0; nt < 4; ++nt) {
      s[nt] = (f32x4){0.f, 0.f, 0.f, 0.f};
      bf16x8 kf0 = *(const bf16x8*)(Ks + nt * 16 * 72 + rdoff[0]);
      bf16x8 kf1 = *(const bf16x8*)(Ks + nt * 16 * 72 + rdoff[1]);
      s[nt] = __builtin_amdgcn_mfma_f32_16x16x32_bf16(qf0, kf0, s[nt], 0, 0, 0);
      s[nt] = __builtin_amdgcn_mfma_f32_16x16x32_bf16(qf1, kf1, s[nt], 0, 0, 0);
    }

    // freq bias + online softmax (lane owns rows lg*4+r, col ln+16*nt)
    float dmv[4];
#pragma unroll
    for (int nt = 0; nt < 4; ++nt) dmv[nt] = dfeat[b * 1024 + kt * 64 + nt * 16 + ln];
#pragma unroll
    for (int r = 0; r < 4; ++r) {
      float sv[4];
#pragma unroll
      for (int nt = 0; nt < 4; ++nt) {
        float fv = fminf(fmaxf(cr[r] * dmv[nt], 0.f), 1.f);
        sv[nt] = iaw * s[nt][r] + aw * fv;
      }
      float mt_ = fmaxf(fmaxf(sv[0], sv[1]), fmaxf(sv[2], sv[3]));
      mt_ = fmaxf(mt_, __shfl_xor(mt_, 1));
      mt_ = fmaxf(mt_, __shfl_xor(mt_, 2));
      mt_ = fmaxf(mt_, __shfl_xor(mt_, 4));
      mt_ = fmaxf(mt_, __shfl_xor(mt_, 8));
      float mnew = fmaxf(mrow[r], mt_);
      float p[4], ts = 0.f;
#pragma unroll
      for (int nt = 0; nt < 4; ++nt) { p[nt] = __expf(sv[nt] - mnew); ts += p[nt]; }
      ts += __shfl_xor(ts, 1);
      ts += __shfl_xor(ts, 2);
      ts += __shfl_xor(ts, 4);
      ts += __shfl_xor(ts, 8);
      float sc = __expf(mrow[r] - mnew);
      lrow[r] = lrow[r] * sc + ts;
      mrow[r] = mnew;
#pragma unroll
      for (int dt = 0; dt < 4; ++dt) accO[dt][r] *= sc;
      int prow = lg * 4 + r;
#pragma unroll
      for (int nt = 0; nt < 4; ++nt) Ps[w][prow * 72 + nt * 16 + ln] = f2bf(p[nt]);
    }

    // PV: A = P (m=ln rows), B = V^T rows (d = dt*16+ln)
    bf16x8 af0 = *(const bf16x8*)(Ps[w] + rdoff[0]);
    bf16x8 af1 = *(const bf16x8*)(Ps[w] + rdoff[1]);
#pragma unroll
    for (int dt = 0; dt < 4; ++dt) {
      bf16x8 vf0 = *(const bf16x8*)(Vs + dt * 16 * 72 + rdoff[0]);
      bf16x8 vf1 = *(const bf16x8*)(Vs + dt * 16 * 72 + rdoff[1]);
      accO[dt] = __builtin_amdgcn_mfma_f32_16x16x32_bf16(af0, vf0, accO[dt], 0, 0, 0);
      accO[dt] = __builtin_amdgcn_mfma_f32_16x16x32_bf16(af1, vf1, accO[dt], 0, 0, 0);
    }
  }

  // epilogue
#pragma unroll
  for (int r = 0; r < 4; ++r) {
    float inv = 1.f / lrow[r];
    int n = qt * 64 + w * 16 + lg * 4 + r;
#pragma unroll
    for (int dt = 0; dt < 4; ++dt)
      ao[((size_t)(b * 1024 + n)) * 512 + h * 64 + dt * 16 + ln] = f2bf(accO[dt][r] * inv);
  }
}

extern "C" void kernel_launch(void* const* d_in, const int* in_sizes, int n_in,
                              void* d_out, int out_size, void* d_ws, size_t ws_size,
                              hipStream_t stream) {
  const float* x      = (const float*)d_in[0];
  const float* qkv_w  = (const float*)d_in[1];
  const float* qkv_b  = (const float*)d_in[2];
  const float* proj_w = (const float*)d_in[3];
  const float* proj_b = (const float*)d_in[4];
  const float* h1_w   = (const float*)d_in[5];
  const float* h1_b   = (const float*)d_in[6];
  const float* h2_w   = (const float*)d_in[7];
  const float* h2_b   = (const float*)d_in[8];
  const float* freq_w = (const float*)d_in[9];

  char* ws = (char*)d_ws;
  unsigned short* xb  = (unsigned short*)(ws + OFF_XB);
  unsigned short* qbp = (unsigned short*)(ws + OFF_QB);
  unsigned short* kbp = (unsigned short*)(ws + OFF_KB);
  unsigned short* vbp = (unsigned short*)(ws + OFF_VB);
  unsigned short* vtg = (unsigned short*)(ws + OFF_VT);
  unsigned short* ao  = (unsigned short*)(ws + OFF_AO);
  unsigned short* wt  = (unsigned short*)(ws + OFF_WT);
  unsigned short* pwt = (unsigned short*)(ws + OFF_PWT);
  float* xmean = (float*)(ws + OFF_XM);
  float* xavg  = (float*)(ws + OFF_XA);
  float* dfeat = (float*)(ws + OFF_DF);
  float* tsum  = (float*)(ws + OFF_TS);
  float* crow  = (float*)(ws + OFF_CR);
  float* out   = (float*)d_out;

  hipMemsetAsync(xavg, 0, 16 * 512 * sizeof(float), stream);

  k_xmean_cvt<<<dim3(4096), 256, 0, stream>>>(x, xmean, xb);
  k_xavg<<<dim3(16, 16), 512, 0, stream>>>(x, xavg);
  k_dct<<<dim3(16), 1024, 0, stream>>>(xmean, dfeat, tsum);
  k_headw<<<dim3(16), 128, 0, stream>>>(xavg, h1_w, h1_b, h2_w, h2_b, dfeat, tsum, crow);
  k_wtrans<<<dim3(24, 8), 256, 0, stream>>>(qkv_w, wt, 1536);
  k_wtrans<<<dim3(8, 8), 256, 0, stream>>>(proj_w, pwt, 512);
  k_gemm<0><<<dim3(12, 128), 256, 0, stream>>>(xb, wt, qkv_b, qbp, kbp, vbp, nullptr);
  k_vtrans<<<dim3(16, 8, 16), 256, 0, stream>>>(vbp, vtg);
  k_attn<<<dim3(16, 8, 16), 256, 0, stream>>>(qbp, kbp, vtg, crow, dfeat, freq_w, ao);
  k_gemm<1><<<dim3(4, 128), 256, 0, stream>>>(ao, pwt, proj_b, nullptr, nullptr, nullptr, out);
}

// Round 7
// 233.366 us; speedup vs baseline: 6.0100x; 1.0183x over previous
//
#include <hip/hip_runtime.h>
#include <hip/hip_bf16.h>
#include <math.h>

#define PI_F  3.14159265358979323846f
#define LOG2E 1.44269504088896340736f

typedef __attribute__((ext_vector_type(8))) short          bf16x8;
typedef __attribute__((ext_vector_type(8))) unsigned short ushort8;
typedef __attribute__((ext_vector_type(4))) float          f32x4;

__device__ __forceinline__ unsigned short f2bf(float f) {
  union { float f; unsigned u; } v; v.f = f;
  unsigned r = v.u + 0x7fffu + ((v.u >> 16) & 1u);
  return (unsigned short)(r >> 16);
}

__device__ __forceinline__ unsigned short f2bf_hw(float f) {
  __hip_bfloat16 h = __float2bfloat16(f);
  return *reinterpret_cast<unsigned short*>(&h);
}

#define GLOAD16(g, l)                                                         \
  __builtin_amdgcn_global_load_lds(                                           \
      (const __attribute__((address_space(1))) void*)(g),                     \
      (__attribute__((address_space(3))) void*)(l), 16, 0, 0)

// ---- workspace layout (BYTE offsets; bf16 = 2 B/elem) ----
static const size_t OFF_XB  = 0;           // bf16 x      (16384,512)   16 MB
static const size_t OFF_QB  = 16777216;    // bf16 q*qscl (B,H,N,64)    16 MB
static const size_t OFF_KB  = 33554432;    // bf16 k                    16 MB
static const size_t OFF_VB  = 50331648;    // bf16 v                    16 MB
static const size_t OFF_VT  = 67108864;    // bf16 v^T    (B,H,64,N)    16 MB
static const size_t OFF_AO  = 83886080;    // bf16 attn out (16384,512) 16 MB
static const size_t OFF_WT  = 100663296;   // bf16 qkv_w^T (1536,512)  1.5 MB
static const size_t OFF_PWT = 102236160;   // bf16 proj_w^T (512,512)  0.5 MB
static const size_t OFF_XM  = 102760448;   // f32 xmean (B,N)
static const size_t OFF_XA  = 102825984;   // f32 xavg  (B,512)
static const size_t OFF_DF  = 102858752;   // f32 dfeat (B,N)
static const size_t OFF_TS  = 102924288;   // f32 tsum  (B)
static const size_t OFF_CR  = 102924352;   // f32 crow2 (B,N)  [pre-scaled by aw*log2e]

// ---------- x row-mean + f32->bf16 convert ----------
__global__ __launch_bounds__(256) void k_xmean_cvt(const float* __restrict__ x,
                                                   float* __restrict__ xmean,
                                                   unsigned short* __restrict__ xb) {
  int row  = blockIdx.x * 4 + (threadIdx.x >> 6);
  int lane = threadIdx.x & 63;
  const float* px = x + (size_t)row * 512 + lane * 8;
  float4 a = ((const float4*)px)[0];
  float4 b = ((const float4*)px)[1];
  ushort8 o;
  o[0] = f2bf(a.x); o[1] = f2bf(a.y); o[2] = f2bf(a.z); o[3] = f2bf(a.w);
  o[4] = f2bf(b.x); o[5] = f2bf(b.y); o[6] = f2bf(b.z); o[7] = f2bf(b.w);
  *(ushort8*)(xb + (size_t)row * 512 + lane * 8) = o;
  float s = a.x + a.y + a.z + a.w + b.x + b.y + b.z + b.w;
  for (int off = 32; off; off >>= 1) s += __shfl_down(s, off);
  if (lane == 0) xmean[row] = s * (1.f / 512.f);
}

// ---------- x column sums over N (partial, atomic) ----------
__global__ __launch_bounds__(512) void k_xavg(const float* __restrict__ x,
                                              float* __restrict__ xavg) {
  int b = blockIdx.x, chunk = blockIdx.y;
  int c = threadIdx.x;
  const float* px = x + ((size_t)b * 1024 + (size_t)chunk * 64) * 512 + c;
  float s = 0.f;
#pragma unroll 8
  for (int n = 0; n < 64; ++n) s += px[(size_t)n * 512];
  atomicAdd(&xavg[b * 512 + c], s);
}

// ---------- DCT feature ----------
__global__ __launch_bounds__(1024) void k_dct(const float* __restrict__ xmean,
                                              float* __restrict__ dfeat,
                                              float* __restrict__ tsum) {
  __shared__ float A[32][33], Dm[32][33], Tm[32][33];
  __shared__ float red[1024];
  __shared__ float nrm;
  int b = blockIdx.x, t = threadIdx.x;
  int kk = t >> 5, nn = t & 31;
  A[kk][nn] = xmean[b * 1024 + t];
  float dv = (kk == 0) ? sqrtf(1.f / 32.f)
                       : sqrtf(2.f / 32.f) * cosf(PI_F * (2.f * nn + 1.f) * (float)kk / 64.f);
  Dm[kk][nn] = dv;
  __syncthreads();
  float acc = 0.f;
  for (int m = 0; m < 32; ++m) acc += Dm[kk][m] * A[m][nn];
  Tm[kk][nn] = acc;
  __syncthreads();
  float acc2 = 0.f;
  for (int n = 0; n < 32; ++n) acc2 += Tm[kk][n] * Dm[nn][n];
  float val = fminf(fmaxf(acc2, -10.f), 10.f);
  red[t] = val * val;
  __syncthreads();
  for (int s = 512; s; s >>= 1) { if (t < s) red[t] += red[t + s]; __syncthreads(); }
  if (t == 0) nrm = sqrtf(red[0]) + 1e-5f;
  __syncthreads();
  float dn = val / nrm;
  dfeat[b * 1024 + t] = dn;
  red[t] = dn;
  __syncthreads();
  for (int s = 512; s; s >>= 1) { if (t < s) red[t] += red[t + s]; __syncthreads(); }
  if (t == 0) tsum[b] = red[0];
}

// ---------- head MLP -> row coefficients (pre-scaled by aw*log2e) ----------
__global__ __launch_bounds__(128) void k_headw(const float* __restrict__ xavg,
                                               const float* __restrict__ h1w,
                                               const float* __restrict__ h1b,
                                               const float* __restrict__ h2w,
                                               const float* __restrict__ h2b,
                                               const float* __restrict__ dfeat,
                                               const float* __restrict__ tsum,
                                               const float* __restrict__ freqw,
                                               float* __restrict__ crow) {
  __shared__ float xa[512];
  __shared__ float h1s[128];
  __shared__ float hw[8];
  int b = blockIdx.x, t = threadIdx.x;
  for (int i = t; i < 512; i += 128) xa[i] = xavg[b * 512 + i] * (1.f / 1024.f);
  __syncthreads();
  float acc = h1b[t];
  for (int c = 0; c < 512; ++c) acc += xa[c] * h1w[c * 128 + t];
  h1s[t] = fmaxf(acc, 0.f);
  __syncthreads();
  if (t < 8) {
    float a2 = h2b[t];
    for (int j = 0; j < 128; ++j) a2 += h1s[j] * h2w[j * 8 + t];
    hw[t] = a2;
  }
  __syncthreads();
  float s = 0.f;
#pragma unroll
  for (int h = 0; h < 8; ++h) s += hw[h] * hw[h];
  float Tb = tsum[b];
  const float aw2 = (1.f / (1.f + __expf(-freqw[0]))) * LOG2E;
  for (int n = t; n < 1024; n += 128) {
    float dn = dfeat[b * 1024 + n];
    float p = s * dn;
    crow[b * 1024 + n] = aw2 * p / fmaxf(p * Tb, 1e-5f);
  }
}

// ---------- weight transpose+convert: w (K,Nw) f32 -> wt (Nw,512) bf16 ----------
__global__ __launch_bounds__(256) void k_wtrans(const float* __restrict__ w,
                                                unsigned short* __restrict__ wt,
                                                int Nw) {
  __shared__ unsigned short T[64 * 65];
  int n0 = blockIdx.x * 64, k0 = blockIdx.y * 64;
  int t = threadIdx.x;
  int r = t >> 2, c0 = (t & 3) * 16;
  const float* src = w + (size_t)(k0 + r) * Nw + n0 + c0;
#pragma unroll
  for (int q = 0; q < 4; ++q) {
    float4 v4 = *(const float4*)(src + q * 4);
    T[(c0 + q * 4 + 0) * 65 + r] = f2bf(v4.x);
    T[(c0 + q * 4 + 1) * 65 + r] = f2bf(v4.y);
    T[(c0 + q * 4 + 2) * 65 + r] = f2bf(v4.z);
    T[(c0 + q * 4 + 3) * 65 + r] = f2bf(v4.w);
  }
  __syncthreads();
  int nl = t >> 2, koff = (t & 3) * 16;
  ushort8 o0, o1;
#pragma unroll
  for (int e = 0; e < 8; ++e) o0[e] = T[nl * 65 + koff + e];
#pragma unroll
  for (int e = 0; e < 8; ++e) o1[e] = T[nl * 65 + koff + 8 + e];
  unsigned short* dst = wt + (size_t)(n0 + nl) * 512 + k0 + koff;
  *(ushort8*)(dst) = o0;
  *(ushort8*)(dst + 8) = o1;
}

// ---------- V transpose: vb (B,H,N,64) -> vtg (B,H,64,N) bf16 ----------
__global__ __launch_bounds__(256) void k_vtrans(const unsigned short* __restrict__ vb,
                                                unsigned short* __restrict__ vtg) {
  __shared__ unsigned short T[64 * 65];
  int nt = blockIdx.x, h = blockIdx.y, b = blockIdx.z;
  size_t plane = ((size_t)(b * 8 + h)) << 16;
  int t = threadIdx.x;
  int r = t >> 2, c0 = (t & 3) * 16;
  const unsigned short* src = vb + plane + (size_t)(nt * 64 + r) * 64 + c0;
  ushort8 v0 = *(const ushort8*)(src);
  ushort8 v1 = *(const ushort8*)(src + 8);
#pragma unroll
  for (int e = 0; e < 8; ++e) T[(c0 + e) * 65 + r] = v0[e];
#pragma unroll
  for (int e = 0; e < 8; ++e) T[(c0 + 8 + e) * 65 + r] = v1[e];
  __syncthreads();
  int d = t >> 2, koff = (t & 3) * 16;
  ushort8 o0, o1;
#pragma unroll
  for (int e = 0; e < 8; ++e) o0[e] = T[d * 65 + koff + e];
#pragma unroll
  for (int e = 0; e < 8; ++e) o1[e] = T[d * 65 + koff + 8 + e];
  unsigned short* dst = vtg + plane + (size_t)d * 1024 + nt * 64 + koff;
  *(ushort8*)(dst) = o0;
  *(ushort8*)(dst + 8) = o1;
}

// ---------- bf16 MFMA GEMM, 128x128, BK=64, global_load_lds + XOR preswizzle ----
// MODE 0: QKV epilogue (bias, q scaled by 0.125*iaw*log2e, split q/k/v bf16)
// MODE 1: proj epilogue (bias, f32 out row-major)
template <int MODE>
__global__ __launch_bounds__(256) void k_gemm(const unsigned short* __restrict__ A,
                                              const unsigned short* __restrict__ Bt,
                                              const float* __restrict__ bias,
                                              const float* __restrict__ freqw,
                                              unsigned short* __restrict__ o_q,
                                              unsigned short* __restrict__ o_k,
                                              unsigned short* __restrict__ o_v,
                                              float* __restrict__ o_f) {
  __shared__ __align__(16) unsigned short As[128 * 64];
  __shared__ __align__(16) unsigned short Bs[128 * 64];
  const int t = threadIdx.x, w = t >> 6, l = t & 63;
  const int lg = l >> 4, ln = l & 15;
  const int wm = w >> 1, wn = w & 1;
  const int row0 = blockIdx.y * 128, col0 = blockIdx.x * 128;

  f32x4 acc[4][4];
#pragma unroll
  for (int i = 0; i < 4; ++i)
#pragma unroll
    for (int j = 0; j < 4; ++j) acc[i][j] = (f32x4){0.f, 0.f, 0.f, 0.f};

  int aoff[4][2], boff[4][2];
#pragma unroll
  for (int mt = 0; mt < 4; ++mt)
#pragma unroll
    for (int ks = 0; ks < 2; ++ks) {
      int ra = wm * 64 + mt * 16 + ln;
      aoff[mt][ks] = ra * 64 + (((lg + ks * 4) ^ (ra & 7)) << 3);
      int rb = wn * 64 + mt * 16 + ln;
      boff[mt][ks] = rb * 64 + (((lg + ks * 4) ^ (rb & 7)) << 3);
    }

  for (int k0 = 0; k0 < 512; k0 += 64) {
#pragma unroll
    for (int j = 0; j < 4; ++j) {
      int g = (j * 4 + w) * 64 + l;  // granule 0..1023
      int row = g >> 3, slot = g & 7;
      int ss = slot ^ (row & 7);
      GLOAD16(A + (size_t)(row0 + row) * 512 + k0 + ss * 8, As + (size_t)(j * 4 + w) * 512);
      GLOAD16(Bt + (size_t)(col0 + row) * 512 + k0 + ss * 8, Bs + (size_t)(j * 4 + w) * 512);
    }
    __syncthreads();
#pragma unroll
    for (int ks = 0; ks < 2; ++ks) {
      bf16x8 av[4], bv[4];
#pragma unroll
      for (int mt = 0; mt < 4; ++mt) av[mt] = *(const bf16x8*)(As + aoff[mt][ks]);
#pragma unroll
      for (int nt = 0; nt < 4; ++nt) bv[nt] = *(const bf16x8*)(Bs + boff[nt][ks]);
#pragma unroll
      for (int mt = 0; mt < 4; ++mt)
#pragma unroll
        for (int nt = 0; nt < 4; ++nt)
          acc[mt][nt] = __builtin_amdgcn_mfma_f32_16x16x32_bf16(av[mt], bv[nt], acc[mt][nt], 0, 0, 0);
    }
    __syncthreads();
  }

  if (MODE == 0) {
    const int sel = col0 >> 9;
    unsigned short* outp = (sel == 0) ? o_q : (sel == 1) ? o_k : o_v;
    const float aw = 1.f / (1.f + __expf(-freqw[0]));
    const float scl = (sel == 0) ? 0.125f * (1.f - aw) * LOG2E : 1.f;
#pragma unroll
    for (int nt = 0; nt < 4; ++nt) {
      int colg = col0 + wn * 64 + nt * 16 + ln;
      float bcol = bias[colg];
      int h = (colg >> 6) & 7, d = colg & 63;
#pragma unroll
      for (int mt = 0; mt < 4; ++mt)
#pragma unroll
        for (int r = 0; r < 4; ++r) {
          int row = row0 + wm * 64 + mt * 16 + lg * 4 + r;
          int bidx = row >> 10, n = row & 1023;
          float val = (acc[mt][nt][r] + bcol) * scl;
          outp[(((size_t)(bidx * 8 + h)) << 16) + (n << 6) + d] = f2bf(val);
        }
    }
  } else {
#pragma unroll
    for (int nt = 0; nt < 4; ++nt) {
      int colg = col0 + wn * 64 + nt * 16 + ln;
      float bcol = bias[colg];
#pragma unroll
      for (int mt = 0; mt < 4; ++mt)
#pragma unroll
        for (int r = 0; r < 4; ++r) {
          int row = row0 + wm * 64 + mt * 16 + lg * 4 + r;
          o_f[(size_t)row * 512 + colg] = acc[mt][nt][r] + bcol;
        }
    }
  }
}

// ---------- flash attention, bf16 MFMA, rank-1 freq bias ----------
// log2-domain logits (scales folded upstream), defer-max (THR=8), gload_lds.
__global__ __launch_bounds__(256) void k_attn(const unsigned short* __restrict__ qb,
                                              const unsigned short* __restrict__ kb,
                                              const unsigned short* __restrict__ vtg,
                                              const float* __restrict__ crow,
                                              const float* __restrict__ dfeat,
                                              const float* __restrict__ freqw,
                                              unsigned short* __restrict__ ao) {
  __shared__ __align__(16) unsigned short Ks[64 * 64];
  __shared__ __align__(16) unsigned short Vs[64 * 64];
  __shared__ __align__(16) unsigned short Ps[4][16 * 64];
  const int qt = blockIdx.x, h = blockIdx.y, b = blockIdx.z;
  const int t = threadIdx.x, w = t >> 6, l = t & 63;
  const int lg = l >> 4, ln = l & 15;
  const size_t base = ((size_t)(b * 8 + h)) << 16;
  const float aw2 = (1.f / (1.f + __expf(-freqw[0]))) * LOG2E;  // clamp upper bound

  // Q fragments in registers (A-operand: m = ln, k-block = lg)
  const int qrow = qt * 64 + w * 16 + ln;
  bf16x8 qf0 = *(const bf16x8*)(qb + base + (size_t)qrow * 64 + lg * 8);
  bf16x8 qf1 = *(const bf16x8*)(qb + base + (size_t)qrow * 64 + lg * 8 + 32);

  float cr2[4];
#pragma unroll
  for (int r = 0; r < 4; ++r) cr2[r] = crow[b * 1024 + qt * 64 + w * 16 + lg * 4 + r];

  f32x4 accO[4];
#pragma unroll
  for (int dt = 0; dt < 4; ++dt) accO[dt] = (f32x4){0.f, 0.f, 0.f, 0.f};
  float mrow[4] = {-1e30f, -1e30f, -1e30f, -1e30f};
  float lrow[4] = {0.f, 0.f, 0.f, 0.f};

  // XOR-swizzled fragment read offsets (row = ln, k-slots lg / lg+4)
  int rdoff[2];
#pragma unroll
  for (int ks = 0; ks < 2; ++ks) rdoff[ks] = ln * 64 + (((lg + ks * 4) ^ (ln & 7)) << 3);
  // P write offsets (row = lg*4+r, col = nt*16+ln, swizzled)
  int pwoff[4][4];
#pragma unroll
  for (int nt = 0; nt < 4; ++nt)
#pragma unroll
    for (int r = 0; r < 4; ++r) {
      int prow = lg * 4 + r;
      pwoff[nt][r] = prow * 64 + ((((nt << 1) | (ln >> 3)) ^ (prow & 7)) << 3) + (ln & 7);
    }

  for (int kt = 0; kt < 16; ++kt) {
    __syncthreads();  // previous tile fully consumed
#pragma unroll
    for (int j = 0; j < 2; ++j) {
      int g = (j * 4 + w) * 64 + l;  // granule 0..511
      int row = g >> 3, slot = g & 7;
      int ss = slot ^ (row & 7);
      GLOAD16(kb + base + (size_t)(kt * 64 + row) * 64 + ss * 8, Ks + (size_t)(j * 4 + w) * 512);
      GLOAD16(vtg + base + (size_t)row * 1024 + kt * 64 + ss * 8, Vs + (size_t)(j * 4 + w) * 512);
    }
    __syncthreads();

    // QK^T: S[q][key] in log2 domain (iaw*log2e folded into q)
    f32x4 s[4];
#pragma unroll
    for (int nt = 0; nt < 4; ++nt) {
      s[nt] = (f32x4){0.f, 0.f, 0.f, 0.f};
      bf16x8 kf0 = *(const bf16x8*)(Ks + nt * 1024 + rdoff[0]);
      bf16x8 kf1 = *(const bf16x8*)(Ks + nt * 1024 + rdoff[1]);
      s[nt] = __builtin_amdgcn_mfma_f32_16x16x32_bf16(qf0, kf0, s[nt], 0, 0, 0);
      s[nt] = __builtin_amdgcn_mfma_f32_16x16x32_bf16(qf1, kf1, s[nt], 0, 0, 0);
    }

    // freq bias add + defer-max online softmax
    float dmv[4];
#pragma unroll
    for (int nt = 0; nt < 4; ++nt) dmv[nt] = dfeat[b * 1024 + kt * 64 + nt * 16 + ln];
#pragma unroll
    for (int nt = 0; nt < 4; ++nt)
#pragma unroll
      for (int r = 0; r < 4; ++r) {
        float fv = fminf(fmaxf(cr2[r] * dmv[nt], 0.f), aw2);
        s[nt][r] = s[nt][r] + fv;
      }
    float lmax[4];
    bool viol = false;
#pragma unroll
    for (int r = 0; r < 4; ++r) {
      lmax[r] = fmaxf(fmaxf(s[0][r], s[1][r]), fmaxf(s[2][r], s[3][r]));
      viol = viol || (lmax[r] > mrow[r] + 8.f);
    }
    if (__any(viol)) {
#pragma unroll
      for (int r = 0; r < 4; ++r) {
        float pmax = lmax[r];
        pmax = fmaxf(pmax, __shfl_xor(pmax, 1));
        pmax = fmaxf(pmax, __shfl_xor(pmax, 2));
        pmax = fmaxf(pmax, __shfl_xor(pmax, 4));
        pmax = fmaxf(pmax, __shfl_xor(pmax, 8));
        float mnew = fmaxf(mrow[r], pmax);
        float sc = exp2f(mrow[r] - mnew);
        lrow[r] *= sc;
        mrow[r] = mnew;
#pragma unroll
        for (int dt = 0; dt < 4; ++dt) accO[dt][r] *= sc;
      }
    }
#pragma unroll
    for (int r = 0; r < 4; ++r) {
      float p[4], ts = 0.f;
#pragma unroll
      for (int nt = 0; nt < 4; ++nt) { p[nt] = exp2f(s[nt][r] - mrow[r]); ts += p[nt]; }
      ts += __shfl_xor(ts, 1);
      ts += __shfl_xor(ts, 2);
      ts += __shfl_xor(ts, 4);
      ts += __shfl_xor(ts, 8);
      lrow[r] += ts;
#pragma unroll
      for (int nt = 0; nt < 4; ++nt) Ps[w][pwoff[nt][r]] = f2bf_hw(p[nt]);
    }

    // PV: A = P (m = ln rows), B = V^T rows (d = dt*16+ln)
    bf16x8 af0 = *(const bf16x8*)(Ps[w] + rdoff[0]);
    bf16x8 af1 = *(const bf16x8*)(Ps[w] + rdoff[1]);
#pragma unroll
    for (int dt = 0; dt < 4; ++dt) {
      bf16x8 vf0 = *(const bf16x8*)(Vs + dt * 1024 + rdoff[0]);
      bf16x8 vf1 = *(const bf16x8*)(Vs + dt * 1024 + rdoff[1]);
      accO[dt] = __builtin_amdgcn_mfma_f32_16x16x32_bf16(af0, vf0, accO[dt], 0, 0, 0);
      accO[dt] = __builtin_amdgcn_mfma_f32_16x16x32_bf16(af1, vf1, accO[dt], 0, 0, 0);
    }
  }

  // epilogue
#pragma unroll
  for (int r = 0; r < 4; ++r) {
    float inv = 1.f / lrow[r];
    int n = qt * 64 + w * 16 + lg * 4 + r;
#pragma unroll
    for (int dt = 0; dt < 4; ++dt)
      ao[((size_t)(b * 1024 + n)) * 512 + h * 64 + dt * 16 + ln] = f2bf(accO[dt][r] * inv);
  }
}

extern "C" void kernel_launch(void* const* d_in, const int* in_sizes, int n_in,
                              void* d_out, int out_size, void* d_ws, size_t ws_size,
                              hipStream_t stream) {
  const float* x      = (const float*)d_in[0];
  const float* qkv_w  = (const float*)d_in[1];
  const float* qkv_b  = (const float*)d_in[2];
  const float* proj_w = (const float*)d_in[3];
  const float* proj_b = (const float*)d_in[4];
  const float* h1_w   = (const float*)d_in[5];
  const float* h1_b   = (const float*)d_in[6];
  const float* h2_w   = (const float*)d_in[7];
  const float* h2_b   = (const float*)d_in[8];
  const float* freq_w = (const float*)d_in[9];

  char* ws = (char*)d_ws;
  unsigned short* xb  = (unsigned short*)(ws + OFF_XB);
  unsigned short* qbp = (unsigned short*)(ws + OFF_QB);
  unsigned short* kbp = (unsigned short*)(ws + OFF_KB);
  unsigned short* vbp = (unsigned short*)(ws + OFF_VB);
  unsigned short* vtg = (unsigned short*)(ws + OFF_VT);
  unsigned short* ao  = (unsigned short*)(ws + OFF_AO);
  unsigned short* wt  = (unsigned short*)(ws + OFF_WT);
  unsigned short* pwt = (unsigned short*)(ws + OFF_PWT);
  float* xmean = (float*)(ws + OFF_XM);
  float* xavg  = (float*)(ws + OFF_XA);
  float* dfeat = (float*)(ws + OFF_DF);
  float* tsum  = (float*)(ws + OFF_TS);
  float* crow  = (float*)(ws + OFF_CR);
  float* out   = (float*)d_out;

  hipMemsetAsync(xavg, 0, 16 * 512 * sizeof(float), stream);

  k_xmean_cvt<<<dim3(4096), 256, 0, stream>>>(x, xmean, xb);
  k_xavg<<<dim3(16, 16), 512, 0, stream>>>(x, xavg);
  k_dct<<<dim3(16), 1024, 0, stream>>>(xmean, dfeat, tsum);
  k_headw<<<dim3(16), 128, 0, stream>>>(xavg, h1_w, h1_b, h2_w, h2_b, dfeat, tsum, freq_w, crow);
  k_wtrans<<<dim3(24, 8), 256, 0, stream>>>(qkv_w, wt, 1536);
  k_wtrans<<<dim3(8, 8), 256, 0, stream>>>(proj_w, pwt, 512);
  k_gemm<0><<<dim3(12, 128), 256, 0, stream>>>(xb, wt, qkv_b, freq_w, qbp, kbp, vbp, nullptr);
  k_vtrans<<<dim3(16, 8, 16), 256, 0, stream>>>(vbp, vtg);
  k_attn<<<dim3(16, 8, 16), 256, 0, stream>>>(qbp, kbp, vtg, crow, dfeat, freq_w, ao);
  k_gemm<1><<<dim3(4, 128), 256, 0, stream>>>(ao, pwt, proj_b, freq_w, nullptr, nullptr, nullptr, out);
}

// Round 8
// 215.513 us; speedup vs baseline: 6.5079x; 1.0828x over previous
//
#include <hip/hip_runtime.h>
#include <hip/hip_bf16.h>
#include <math.h>

#define PI_F  3.14159265358979323846f
#define LOG2E 1.44269504088896340736f

typedef __attribute__((ext_vector_type(8))) short          bf16x8;
typedef __attribute__((ext_vector_type(8))) unsigned short ushort8;
typedef __attribute__((ext_vector_type(4))) float          f32x4;

__device__ __forceinline__ unsigned short f2bf(float f) {
  union { float f; unsigned u; } v; v.f = f;
  unsigned r = v.u + 0x7fffu + ((v.u >> 16) & 1u);
  return (unsigned short)(r >> 16);
}

__device__ __forceinline__ unsigned short f2bf_hw(float f) {
  __hip_bfloat16 h = __float2bfloat16(f);
  return *reinterpret_cast<unsigned short*>(&h);
}

#define GLOAD16(g, l)                                                         \
  __builtin_amdgcn_global_load_lds(                                           \
      (const __attribute__((address_space(1))) void*)(g),                     \
      (__attribute__((address_space(3))) void*)(l), 16, 0, 0)

// ---- workspace layout (BYTE offsets; bf16 = 2 B/elem) ----
static const size_t OFF_XB  = 0;           // bf16 x      (16384,512)   16 MB
static const size_t OFF_QB  = 16777216;    // bf16 q*qscl (B,H,N,64)    16 MB
static const size_t OFF_KB  = 33554432;    // bf16 k                    16 MB
static const size_t OFF_VB  = 50331648;    // bf16 v                    16 MB
static const size_t OFF_VT  = 67108864;    // bf16 v^T    (B,H,64,N)    16 MB
static const size_t OFF_AO  = 83886080;    // bf16 attn out (16384,512) 16 MB
static const size_t OFF_WT  = 100663296;   // bf16 qkv_w^T (1536,512)  1.5 MB
static const size_t OFF_PWT = 102236160;   // bf16 proj_w^T (512,512)  0.5 MB
static const size_t OFF_XM  = 102760448;   // f32 xmean (B,N)
static const size_t OFF_XA  = 102825984;   // f32 xavg  (B,512)
static const size_t OFF_DF  = 102858752;   // f32 dfeat (B,N)
static const size_t OFF_TS  = 102924288;   // f32 tsum  (B)
static const size_t OFF_CR  = 102924352;   // f32 crow2 (B,N)  [pre-scaled by aw*log2e]

// ---------- x row-mean + f32->bf16 convert ----------
__global__ __launch_bounds__(256) void k_xmean_cvt(const float* __restrict__ x,
                                                   float* __restrict__ xmean,
                                                   unsigned short* __restrict__ xb) {
  int row  = blockIdx.x * 4 + (threadIdx.x >> 6);
  int lane = threadIdx.x & 63;
  const float* px = x + (size_t)row * 512 + lane * 8;
  float4 a = ((const float4*)px)[0];
  float4 b = ((const float4*)px)[1];
  ushort8 o;
  o[0] = f2bf(a.x); o[1] = f2bf(a.y); o[2] = f2bf(a.z); o[3] = f2bf(a.w);
  o[4] = f2bf(b.x); o[5] = f2bf(b.y); o[6] = f2bf(b.z); o[7] = f2bf(b.w);
  *(ushort8*)(xb + (size_t)row * 512 + lane * 8) = o;
  float s = a.x + a.y + a.z + a.w + b.x + b.y + b.z + b.w;
  for (int off = 32; off; off >>= 1) s += __shfl_down(s, off);
  if (lane == 0) xmean[row] = s * (1.f / 512.f);
}

// ---------- x column sums over N from bf16 xb (partial, atomic) ----------
__global__ __launch_bounds__(512) void k_xavg(const unsigned short* __restrict__ xb,
                                              float* __restrict__ xavg) {
  int b = blockIdx.x, chunk = blockIdx.y;
  int c = threadIdx.x;
  const unsigned short* px = xb + ((size_t)b * 1024 + (size_t)chunk * 64) * 512 + c;
  float s = 0.f;
#pragma unroll 8
  for (int n = 0; n < 64; ++n) {
    unsigned u = (unsigned)px[(size_t)n * 512] << 16;
    s += *reinterpret_cast<float*>(&u);
  }
  atomicAdd(&xavg[b * 512 + c], s);
}

// ---------- DCT feature ----------
__global__ __launch_bounds__(1024) void k_dct(const float* __restrict__ xmean,
                                              float* __restrict__ dfeat,
                                              float* __restrict__ tsum) {
  __shared__ float A[32][33], Dm[32][33], Tm[32][33];
  __shared__ float red[1024];
  __shared__ float nrm;
  int b = blockIdx.x, t = threadIdx.x;
  int kk = t >> 5, nn = t & 31;
  A[kk][nn] = xmean[b * 1024 + t];
  float dv = (kk == 0) ? sqrtf(1.f / 32.f)
                       : sqrtf(2.f / 32.f) * cosf(PI_F * (2.f * nn + 1.f) * (float)kk / 64.f);
  Dm[kk][nn] = dv;
  __syncthreads();
  float acc = 0.f;
  for (int m = 0; m < 32; ++m) acc += Dm[kk][m] * A[m][nn];
  Tm[kk][nn] = acc;
  __syncthreads();
  float acc2 = 0.f;
  for (int n = 0; n < 32; ++n) acc2 += Tm[kk][n] * Dm[nn][n];
  float val = fminf(fmaxf(acc2, -10.f), 10.f);
  red[t] = val * val;
  __syncthreads();
  for (int s = 512; s; s >>= 1) { if (t < s) red[t] += red[t + s]; __syncthreads(); }
  if (t == 0) nrm = sqrtf(red[0]) + 1e-5f;
  __syncthreads();
  float dn = val / nrm;
  dfeat[b * 1024 + t] = dn;
  red[t] = dn;
  __syncthreads();
  for (int s = 512; s; s >>= 1) { if (t < s) red[t] += red[t + s]; __syncthreads(); }
  if (t == 0) tsum[b] = red[0];
}

// ---------- head MLP -> row coefficients (pre-scaled by aw*log2e) ----------
__global__ __launch_bounds__(128) void k_headw(const float* __restrict__ xavg,
                                               const float* __restrict__ h1w,
                                               const float* __restrict__ h1b,
                                               const float* __restrict__ h2w,
                                               const float* __restrict__ h2b,
                                               const float* __restrict__ dfeat,
                                               const float* __restrict__ tsum,
                                               const float* __restrict__ freqw,
                                               float* __restrict__ crow) {
  __shared__ float xa[512];
  __shared__ float h1s[128];
  __shared__ float hw[8];
  int b = blockIdx.x, t = threadIdx.x;
  for (int i = t; i < 512; i += 128) xa[i] = xavg[b * 512 + i] * (1.f / 1024.f);
  __syncthreads();
  float acc = h1b[t];
  for (int c = 0; c < 512; ++c) acc += xa[c] * h1w[c * 128 + t];
  h1s[t] = fmaxf(acc, 0.f);
  __syncthreads();
  if (t < 8) {
    float a2 = h2b[t];
    for (int j = 0; j < 128; ++j) a2 += h1s[j] * h2w[j * 8 + t];
    hw[t] = a2;
  }
  __syncthreads();
  float s = 0.f;
#pragma unroll
  for (int h = 0; h < 8; ++h) s += hw[h] * hw[h];
  float Tb = tsum[b];
  const float aw2 = (1.f / (1.f + __expf(-freqw[0]))) * LOG2E;
  for (int n = t; n < 1024; n += 128) {
    float dn = dfeat[b * 1024 + n];
    float p = s * dn;
    crow[b * 1024 + n] = aw2 * p / fmaxf(p * Tb, 1e-5f);
  }
}

// ---------- weight transpose+convert: w (K,Nw) f32 -> wt (Nw,512) bf16 ----------
__global__ __launch_bounds__(256) void k_wtrans(const float* __restrict__ w,
                                                unsigned short* __restrict__ wt,
                                                int Nw) {
  __shared__ unsigned short T[64 * 65];
  int n0 = blockIdx.x * 64, k0 = blockIdx.y * 64;
  int t = threadIdx.x;
  int r = t >> 2, c0 = (t & 3) * 16;
  const float* src = w + (size_t)(k0 + r) * Nw + n0 + c0;
#pragma unroll
  for (int q = 0; q < 4; ++q) {
    float4 v4 = *(const float4*)(src + q * 4);
    T[(c0 + q * 4 + 0) * 65 + r] = f2bf(v4.x);
    T[(c0 + q * 4 + 1) * 65 + r] = f2bf(v4.y);
    T[(c0 + q * 4 + 2) * 65 + r] = f2bf(v4.z);
    T[(c0 + q * 4 + 3) * 65 + r] = f2bf(v4.w);
  }
  __syncthreads();
  int nl = t >> 2, koff = (t & 3) * 16;
  ushort8 o0, o1;
#pragma unroll
  for (int e = 0; e < 8; ++e) o0[e] = T[nl * 65 + koff + e];
#pragma unroll
  for (int e = 0; e < 8; ++e) o1[e] = T[nl * 65 + koff + 8 + e];
  unsigned short* dst = wt + (size_t)(n0 + nl) * 512 + k0 + koff;
  *(ushort8*)(dst) = o0;
  *(ushort8*)(dst + 8) = o1;
}

// ---------- V transpose: vb (B,H,N,64) -> vtg (B,H,64,N) bf16 ----------
__global__ __launch_bounds__(256) void k_vtrans(const unsigned short* __restrict__ vb,
                                                unsigned short* __restrict__ vtg) {
  __shared__ unsigned short T[64 * 65];
  int nt = blockIdx.x, h = blockIdx.y, b = blockIdx.z;
  size_t plane = ((size_t)(b * 8 + h)) << 16;
  int t = threadIdx.x;
  int r = t >> 2, c0 = (t & 3) * 16;
  const unsigned short* src = vb + plane + (size_t)(nt * 64 + r) * 64 + c0;
  ushort8 v0 = *(const ushort8*)(src);
  ushort8 v1 = *(const ushort8*)(src + 8);
#pragma unroll
  for (int e = 0; e < 8; ++e) T[(c0 + e) * 65 + r] = v0[e];
#pragma unroll
  for (int e = 0; e < 8; ++e) T[(c0 + 8 + e) * 65 + r] = v1[e];
  __syncthreads();
  int d = t >> 2, koff = (t & 3) * 16;
  ushort8 o0, o1;
#pragma unroll
  for (int e = 0; e < 8; ++e) o0[e] = T[d * 65 + koff + e];
#pragma unroll
  for (int e = 0; e < 8; ++e) o1[e] = T[d * 65 + koff + 8 + e];
  unsigned short* dst = vtg + plane + (size_t)d * 1024 + nt * 64 + koff;
  *(ushort8*)(dst) = o0;
  *(ushort8*)(dst + 8) = o1;
}

// ---------- bf16 MFMA GEMM, 128x128, BK=64, global_load_lds + XOR preswizzle ----
template <int MODE>
__global__ __launch_bounds__(256) void k_gemm(const unsigned short* __restrict__ A,
                                              const unsigned short* __restrict__ Bt,
                                              const float* __restrict__ bias,
                                              const float* __restrict__ freqw,
                                              unsigned short* __restrict__ o_q,
                                              unsigned short* __restrict__ o_k,
                                              unsigned short* __restrict__ o_v,
                                              float* __restrict__ o_f) {
  __shared__ __align__(16) unsigned short As[128 * 64];
  __shared__ __align__(16) unsigned short Bs[128 * 64];
  const int t = threadIdx.x, w = t >> 6, l = t & 63;
  const int lg = l >> 4, ln = l & 15;
  const int wm = w >> 1, wn = w & 1;
  const int row0 = blockIdx.y * 128, col0 = blockIdx.x * 128;

  f32x4 acc[4][4];
#pragma unroll
  for (int i = 0; i < 4; ++i)
#pragma unroll
    for (int j = 0; j < 4; ++j) acc[i][j] = (f32x4){0.f, 0.f, 0.f, 0.f};

  int aoff[4][2], boff[4][2];
#pragma unroll
  for (int mt = 0; mt < 4; ++mt)
#pragma unroll
    for (int ks = 0; ks < 2; ++ks) {
      int ra = wm * 64 + mt * 16 + ln;
      aoff[mt][ks] = ra * 64 + (((lg + ks * 4) ^ (ra & 7)) << 3);
      int rb = wn * 64 + mt * 16 + ln;
      boff[mt][ks] = rb * 64 + (((lg + ks * 4) ^ (rb & 7)) << 3);
    }

  for (int k0 = 0; k0 < 512; k0 += 64) {
#pragma unroll
    for (int j = 0; j < 4; ++j) {
      int g = (j * 4 + w) * 64 + l;
      int row = g >> 3, slot = g & 7;
      int ss = slot ^ (row & 7);
      GLOAD16(A + (size_t)(row0 + row) * 512 + k0 + ss * 8, As + (size_t)(j * 4 + w) * 512);
      GLOAD16(Bt + (size_t)(col0 + row) * 512 + k0 + ss * 8, Bs + (size_t)(j * 4 + w) * 512);
    }
    __syncthreads();
#pragma unroll
    for (int ks = 0; ks < 2; ++ks) {
      bf16x8 av[4], bv[4];
#pragma unroll
      for (int mt = 0; mt < 4; ++mt) av[mt] = *(const bf16x8*)(As + aoff[mt][ks]);
#pragma unroll
      for (int nt = 0; nt < 4; ++nt) bv[nt] = *(const bf16x8*)(Bs + boff[nt][ks]);
#pragma unroll
      for (int mt = 0; mt < 4; ++mt)
#pragma unroll
        for (int nt = 0; nt < 4; ++nt)
          acc[mt][nt] = __builtin_amdgcn_mfma_f32_16x16x32_bf16(av[mt], bv[nt], acc[mt][nt], 0, 0, 0);
    }
    __syncthreads();
  }

  if (MODE == 0) {
    const int sel = col0 >> 9;
    unsigned short* outp = (sel == 0) ? o_q : (sel == 1) ? o_k : o_v;
    const float aw = 1.f / (1.f + __expf(-freqw[0]));
    const float scl = (sel == 0) ? 0.125f * (1.f - aw) * LOG2E : 1.f;
#pragma unroll
    for (int nt = 0; nt < 4; ++nt) {
      int colg = col0 + wn * 64 + nt * 16 + ln;
      float bcol = bias[colg];
      int h = (colg >> 6) & 7, d = colg & 63;
#pragma unroll
      for (int mt = 0; mt < 4; ++mt)
#pragma unroll
        for (int r = 0; r < 4; ++r) {
          int row = row0 + wm * 64 + mt * 16 + lg * 4 + r;
          int bidx = row >> 10, n = row & 1023;
          float val = (acc[mt][nt][r] + bcol) * scl;
          outp[(((size_t)(bidx * 8 + h)) << 16) + (n << 6) + d] = f2bf(val);
        }
    }
  } else {
#pragma unroll
    for (int nt = 0; nt < 4; ++nt) {
      int colg = col0 + wn * 64 + nt * 16 + ln;
      float bcol = bias[colg];
#pragma unroll
      for (int mt = 0; mt < 4; ++mt)
#pragma unroll
        for (int r = 0; r < 4; ++r) {
          int row = row0 + wm * 64 + mt * 16 + lg * 4 + r;
          o_f[(size_t)row * 512 + colg] = acc[mt][nt][r] + bcol;
        }
    }
  }
}

// ---------- flash attention, QBLK=128: 4 waves x 32 q-rows (2 m-tiles/wave) ---
// log2-domain, bias as MFMA C-init, defer-max (THR=8), deferred lrow reduce.
__global__ __launch_bounds__(256) void k_attn(const unsigned short* __restrict__ qb,
                                              const unsigned short* __restrict__ kb,
                                              const unsigned short* __restrict__ vtg,
                                              const float* __restrict__ crow,
                                              const float* __restrict__ dfeat,
                                              const float* __restrict__ freqw,
                                              unsigned short* __restrict__ ao) {
  __shared__ __align__(16) unsigned short Ks[64 * 64];
  __shared__ __align__(16) unsigned short Vs[64 * 64];
  __shared__ __align__(16) unsigned short Ps[4][32 * 64];
  const int qt = blockIdx.x, h = blockIdx.y, b = blockIdx.z;
  const int t = threadIdx.x, w = t >> 6, l = t & 63;
  const int lg = l >> 4, ln = l & 15;
  const size_t base = ((size_t)(b * 8 + h)) << 16;
  const float aw2 = (1.f / (1.f + __expf(-freqw[0]))) * LOG2E;

  // Q fragments: 2 m-tiles x 2 k-slots (A-operand: row = ln, 8 contig k)
  const int qrow0 = qt * 128 + w * 32;
  bf16x8 qf[2][2];
#pragma unroll
  for (int mt = 0; mt < 2; ++mt)
#pragma unroll
    for (int ks = 0; ks < 2; ++ks)
      qf[mt][ks] = *(const bf16x8*)(qb + base + (size_t)(qrow0 + mt * 16 + ln) * 64 + lg * 8 + ks * 32);

  float cr2[2][4];
#pragma unroll
  for (int mt = 0; mt < 2; ++mt)
#pragma unroll
    for (int r = 0; r < 4; ++r)
      cr2[mt][r] = crow[b * 1024 + qrow0 + mt * 16 + lg * 4 + r];

  f32x4 accO[2][4];
#pragma unroll
  for (int mt = 0; mt < 2; ++mt)
#pragma unroll
    for (int dt = 0; dt < 4; ++dt) accO[mt][dt] = (f32x4){0.f, 0.f, 0.f, 0.f};
  float mrow[2][4], psum[2][4];
#pragma unroll
  for (int mt = 0; mt < 2; ++mt)
#pragma unroll
    for (int r = 0; r < 4; ++r) { mrow[mt][r] = -1e30f; psum[mt][r] = 0.f; }

  // XOR-swizzled fragment read offsets (row = ln; +16 rows preserves row&7)
  int rdoff[2];
#pragma unroll
  for (int ks = 0; ks < 2; ++ks) rdoff[ks] = ln * 64 + (((lg + ks * 4) ^ (ln & 7)) << 3);
  // P write offsets (row = lg*4+r; mt=1 adds 1024, row&7 unchanged)
  int pwoff[4][4];
#pragma unroll
  for (int nt = 0; nt < 4; ++nt)
#pragma unroll
    for (int r = 0; r < 4; ++r) {
      int prow = lg * 4 + r;
      pwoff[nt][r] = prow * 64 + ((((nt << 1) | (ln >> 3)) ^ (prow & 7)) << 3) + (ln & 7);
    }

  for (int kt = 0; kt < 16; ++kt) {
    __syncthreads();
#pragma unroll
    for (int j = 0; j < 2; ++j) {
      int g = (j * 4 + w) * 64 + l;
      int row = g >> 3, slot = g & 7;
      int ss = slot ^ (row & 7);
      GLOAD16(kb + base + (size_t)(kt * 64 + row) * 64 + ss * 8, Ks + (size_t)(j * 4 + w) * 512);
      GLOAD16(vtg + base + (size_t)row * 1024 + kt * 64 + ss * 8, Vs + (size_t)(j * 4 + w) * 512);
    }
    __syncthreads();

    // bias -> C-init, then QK^T with K-fragments shared across m-tiles
    float dmv[4];
#pragma unroll
    for (int nt = 0; nt < 4; ++nt) dmv[nt] = dfeat[b * 1024 + kt * 64 + nt * 16 + ln];
    f32x4 s[2][4];
#pragma unroll
    for (int mt = 0; mt < 2; ++mt)
#pragma unroll
      for (int nt = 0; nt < 4; ++nt)
#pragma unroll
        for (int r = 0; r < 4; ++r)
          s[mt][nt][r] = fminf(fmaxf(cr2[mt][r] * dmv[nt], 0.f), aw2);
#pragma unroll
    for (int nt = 0; nt < 4; ++nt) {
      bf16x8 kf0 = *(const bf16x8*)(Ks + nt * 1024 + rdoff[0]);
      bf16x8 kf1 = *(const bf16x8*)(Ks + nt * 1024 + rdoff[1]);
#pragma unroll
      for (int mt = 0; mt < 2; ++mt) {
        s[mt][nt] = __builtin_amdgcn_mfma_f32_16x16x32_bf16(qf[mt][0], kf0, s[mt][nt], 0, 0, 0);
        s[mt][nt] = __builtin_amdgcn_mfma_f32_16x16x32_bf16(qf[mt][1], kf1, s[mt][nt], 0, 0, 0);
      }
    }

    // defer-max online softmax
    float lmax[2][4];
    bool viol = false;
#pragma unroll
    for (int mt = 0; mt < 2; ++mt)
#pragma unroll
      for (int r = 0; r < 4; ++r) {
        lmax[mt][r] = fmaxf(fmaxf(s[mt][0][r], s[mt][1][r]), fmaxf(s[mt][2][r], s[mt][3][r]));
        viol = viol || (lmax[mt][r] > mrow[mt][r] + 8.f);
      }
    if (__any(viol)) {
#pragma unroll
      for (int mt = 0; mt < 2; ++mt)
#pragma unroll
        for (int r = 0; r < 4; ++r) {
          float pmax = lmax[mt][r];
          pmax = fmaxf(pmax, __shfl_xor(pmax, 1));
          pmax = fmaxf(pmax, __shfl_xor(pmax, 2));
          pmax = fmaxf(pmax, __shfl_xor(pmax, 4));
          pmax = fmaxf(pmax, __shfl_xor(pmax, 8));
          float mnew = fmaxf(mrow[mt][r], pmax);
          float sc = exp2f(mrow[mt][r] - mnew);
          psum[mt][r] *= sc;
          mrow[mt][r] = mnew;
#pragma unroll
          for (int dt = 0; dt < 4; ++dt) accO[mt][dt][r] *= sc;
        }
    }
#pragma unroll
    for (int mt = 0; mt < 2; ++mt)
#pragma unroll
      for (int r = 0; r < 4; ++r) {
        float p0 = exp2f(s[mt][0][r] - mrow[mt][r]);
        float p1 = exp2f(s[mt][1][r] - mrow[mt][r]);
        float p2 = exp2f(s[mt][2][r] - mrow[mt][r]);
        float p3 = exp2f(s[mt][3][r] - mrow[mt][r]);
        psum[mt][r] += (p0 + p1) + (p2 + p3);
        Ps[w][mt * 1024 + pwoff[0][r]] = f2bf_hw(p0);
        Ps[w][mt * 1024 + pwoff[1][r]] = f2bf_hw(p1);
        Ps[w][mt * 1024 + pwoff[2][r]] = f2bf_hw(p2);
        Ps[w][mt * 1024 + pwoff[3][r]] = f2bf_hw(p3);
      }

    // PV with V-fragments shared across m-tiles
    bf16x8 pa[2][2];
#pragma unroll
    for (int mt = 0; mt < 2; ++mt)
#pragma unroll
      for (int ks = 0; ks < 2; ++ks)
        pa[mt][ks] = *(const bf16x8*)(Ps[w] + mt * 1024 + rdoff[ks]);
#pragma unroll
    for (int dt = 0; dt < 4; ++dt) {
      bf16x8 vf0 = *(const bf16x8*)(Vs + dt * 1024 + rdoff[0]);
      bf16x8 vf1 = *(const bf16x8*)(Vs + dt * 1024 + rdoff[1]);
#pragma unroll
      for (int mt = 0; mt < 2; ++mt) {
        accO[mt][dt] = __builtin_amdgcn_mfma_f32_16x16x32_bf16(pa[mt][0], vf0, accO[mt][dt], 0, 0, 0);
        accO[mt][dt] = __builtin_amdgcn_mfma_f32_16x16x32_bf16(pa[mt][1], vf1, accO[mt][dt], 0, 0, 0);
      }
    }
  }

  // epilogue: one cross-lane lrow reduce, then normalize + store
#pragma unroll
  for (int mt = 0; mt < 2; ++mt)
#pragma unroll
    for (int r = 0; r < 4; ++r) {
      float lr = psum[mt][r];
      lr += __shfl_xor(lr, 1);
      lr += __shfl_xor(lr, 2);
      lr += __shfl_xor(lr, 4);
      lr += __shfl_xor(lr, 8);
      float inv = 1.f / lr;
      int n = qrow0 + mt * 16 + lg * 4 + r;
#pragma unroll
      for (int dt = 0; dt < 4; ++dt)
        ao[((size_t)(b * 1024 + n)) * 512 + h * 64 + dt * 16 + ln] = f2bf(accO[mt][dt][r] * inv);
    }
}

extern "C" void kernel_launch(void* const* d_in, const int* in_sizes, int n_in,
                              void* d_out, int out_size, void* d_ws, size_t ws_size,
                              hipStream_t stream) {
  const float* x      = (const float*)d_in[0];
  const float* qkv_w  = (const float*)d_in[1];
  const float* qkv_b  = (const float*)d_in[2];
  const float* proj_w = (const float*)d_in[3];
  const float* proj_b = (const float*)d_in[4];
  const float* h1_w   = (const float*)d_in[5];
  const float* h1_b   = (const float*)d_in[6];
  const float* h2_w   = (const float*)d_in[7];
  const float* h2_b   = (const float*)d_in[8];
  const float* freq_w = (const float*)d_in[9];

  char* ws = (char*)d_ws;
  unsigned short* xb  = (unsigned short*)(ws + OFF_XB);
  unsigned short* qbp = (unsigned short*)(ws + OFF_QB);
  unsigned short* kbp = (unsigned short*)(ws + OFF_KB);
  unsigned short* vbp = (unsigned short*)(ws + OFF_VB);
  unsigned short* vtg = (unsigned short*)(ws + OFF_VT);
  unsigned short* ao  = (unsigned short*)(ws + OFF_AO);
  unsigned short* wt  = (unsigned short*)(ws + OFF_WT);
  unsigned short* pwt = (unsigned short*)(ws + OFF_PWT);
  float* xmean = (float*)(ws + OFF_XM);
  float* xavg  = (float*)(ws + OFF_XA);
  float* dfeat = (float*)(ws + OFF_DF);
  float* tsum  = (float*)(ws + OFF_TS);
  float* crow  = (float*)(ws + OFF_CR);
  float* out   = (float*)d_out;

  hipMemsetAsync(xavg, 0, 16 * 512 * sizeof(float), stream);

  k_xmean_cvt<<<dim3(4096), 256, 0, stream>>>(x, xmean, xb);
  k_xavg<<<dim3(16, 16), 512, 0, stream>>>(xb, xavg);
  k_dct<<<dim3(16), 1024, 0, stream>>>(xmean, dfeat, tsum);
  k_headw<<<dim3(16), 128, 0, stream>>>(xavg, h1_w, h1_b, h2_w, h2_b, dfeat, tsum, freq_w, crow);
  k_wtrans<<<dim3(24, 8), 256, 0, stream>>>(qkv_w, wt, 1536);
  k_wtrans<<<dim3(8, 8), 256, 0, stream>>>(proj_w, pwt, 512);
  k_gemm<0><<<dim3(12, 128), 256, 0, stream>>>(xb, wt, qkv_b, freq_w, qbp, kbp, vbp, nullptr);
  k_vtrans<<<dim3(16, 8, 16), 256, 0, stream>>>(vbp, vtg);
  k_attn<<<dim3(8, 8, 16), 256, 0, stream>>>(qbp, kbp, vtg, crow, dfeat, freq_w, ao);
  k_gemm<1><<<dim3(4, 128), 256, 0, stream>>>(ao, pwt, proj_b, freq_w, nullptr, nullptr, nullptr, out);
}

// Round 9
// 204.287 us; speedup vs baseline: 6.8655x; 1.0550x over previous
//
#include <hip/hip_runtime.h>
#include <hip/hip_bf16.h>
#include <math.h>

#define PI_F  3.14159265358979323846f
#define LOG2E 1.44269504088896340736f

typedef __attribute__((ext_vector_type(8))) short          bf16x8;
typedef __attribute__((ext_vector_type(8))) unsigned short ushort8;
typedef __attribute__((ext_vector_type(4))) float          f32x4;

__device__ __forceinline__ unsigned short f2bf(float f) {
  union { float f; unsigned u; } v; v.f = f;
  unsigned r = v.u + 0x7fffu + ((v.u >> 16) & 1u);
  return (unsigned short)(r >> 16);
}

__device__ __forceinline__ unsigned short f2bf_hw(float f) {
  __hip_bfloat16 h = __float2bfloat16(f);
  return *reinterpret_cast<unsigned short*>(&h);
}

#define GLOAD16(g, l)                                                         \
  __builtin_amdgcn_global_load_lds(                                           \
      (const __attribute__((address_space(1))) void*)(g),                     \
      (__attribute__((address_space(3))) void*)(l), 16, 0, 0)

// ---- workspace layout (BYTE offsets; bf16 = 2 B/elem) ----
static const size_t OFF_XB  = 0;           // bf16 x      (16384,512)   16 MB
static const size_t OFF_QB  = 16777216;    // bf16 q*qscl (B,H,N,64)    16 MB
static const size_t OFF_KB  = 33554432;    // bf16 k                    16 MB
static const size_t OFF_VT  = 67108864;    // bf16 v^T    (B,H,64,N)    16 MB
static const size_t OFF_AO  = 83886080;    // bf16 attn out (16384,512) 16 MB
static const size_t OFF_WT  = 100663296;   // bf16 qkv_w^T (1536,512)  1.5 MB
static const size_t OFF_PWT = 102236160;   // bf16 proj_w^T (512,512)  0.5 MB
static const size_t OFF_XM  = 102760448;   // f32 xmean (B,N)
static const size_t OFF_XA  = 102825984;   // f32 xavg  (B,512)
static const size_t OFF_DF  = 102858752;   // f32 dfeat (B,N)
static const size_t OFF_TS  = 102924288;   // f32 tsum  (B)
static const size_t OFF_CR  = 102924352;   // f32 crow2 (B,N)  [pre-scaled by aw*log2e]

// ---------- x row-mean + f32->bf16 convert ----------
__global__ __launch_bounds__(256) void k_xmean_cvt(const float* __restrict__ x,
                                                   float* __restrict__ xmean,
                                                   unsigned short* __restrict__ xb) {
  int row  = blockIdx.x * 4 + (threadIdx.x >> 6);
  int lane = threadIdx.x & 63;
  const float* px = x + (size_t)row * 512 + lane * 8;
  float4 a = ((const float4*)px)[0];
  float4 b = ((const float4*)px)[1];
  ushort8 o;
  o[0] = f2bf(a.x); o[1] = f2bf(a.y); o[2] = f2bf(a.z); o[3] = f2bf(a.w);
  o[4] = f2bf(b.x); o[5] = f2bf(b.y); o[6] = f2bf(b.z); o[7] = f2bf(b.w);
  *(ushort8*)(xb + (size_t)row * 512 + lane * 8) = o;
  float s = a.x + a.y + a.z + a.w + b.x + b.y + b.z + b.w;
  for (int off = 32; off; off >>= 1) s += __shfl_down(s, off);
  if (lane == 0) xmean[row] = s * (1.f / 512.f);
}

// ---------- x column sums over N from bf16 xb (partial, atomic) ----------
__global__ __launch_bounds__(512) void k_xavg(const unsigned short* __restrict__ xb,
                                              float* __restrict__ xavg) {
  int b = blockIdx.x, chunk = blockIdx.y;
  int c = threadIdx.x;
  const unsigned short* px = xb + ((size_t)b * 1024 + (size_t)chunk * 64) * 512 + c;
  float s = 0.f;
#pragma unroll 8
  for (int n = 0; n < 64; ++n) {
    unsigned u = (unsigned)px[(size_t)n * 512] << 16;
    s += *reinterpret_cast<float*>(&u);
  }
  atomicAdd(&xavg[b * 512 + c], s);
}

// ---------- DCT feature ----------
__global__ __launch_bounds__(1024) void k_dct(const float* __restrict__ xmean,
                                              float* __restrict__ dfeat,
                                              float* __restrict__ tsum) {
  __shared__ float A[32][33], Dm[32][33], Tm[32][33];
  __shared__ float red[1024];
  __shared__ float nrm;
  int b = blockIdx.x, t = threadIdx.x;
  int kk = t >> 5, nn = t & 31;
  A[kk][nn] = xmean[b * 1024 + t];
  float dv = (kk == 0) ? sqrtf(1.f / 32.f)
                       : sqrtf(2.f / 32.f) * cosf(PI_F * (2.f * nn + 1.f) * (float)kk / 64.f);
  Dm[kk][nn] = dv;
  __syncthreads();
  float acc = 0.f;
  for (int m = 0; m < 32; ++m) acc += Dm[kk][m] * A[m][nn];
  Tm[kk][nn] = acc;
  __syncthreads();
  float acc2 = 0.f;
  for (int n = 0; n < 32; ++n) acc2 += Tm[kk][n] * Dm[nn][n];
  float val = fminf(fmaxf(acc2, -10.f), 10.f);
  red[t] = val * val;
  __syncthreads();
  for (int s = 512; s; s >>= 1) { if (t < s) red[t] += red[t + s]; __syncthreads(); }
  if (t == 0) nrm = sqrtf(red[0]) + 1e-5f;
  __syncthreads();
  float dn = val / nrm;
  dfeat[b * 1024 + t] = dn;
  red[t] = dn;
  __syncthreads();
  for (int s = 512; s; s >>= 1) { if (t < s) red[t] += red[t + s]; __syncthreads(); }
  if (t == 0) tsum[b] = red[0];
}

// ---------- head MLP -> row coefficients (pre-scaled by aw*log2e) ----------
__global__ __launch_bounds__(128) void k_headw(const float* __restrict__ xavg,
                                               const float* __restrict__ h1w,
                                               const float* __restrict__ h1b,
                                               const float* __restrict__ h2w,
                                               const float* __restrict__ h2b,
                                               const float* __restrict__ dfeat,
                                               const float* __restrict__ tsum,
                                               const float* __restrict__ freqw,
                                               float* __restrict__ crow) {
  __shared__ float xa[512];
  __shared__ float h1s[128];
  __shared__ float hw[8];
  int b = blockIdx.x, t = threadIdx.x;
  for (int i = t; i < 512; i += 128) xa[i] = xavg[b * 512 + i] * (1.f / 1024.f);
  __syncthreads();
  float acc = h1b[t];
  for (int c = 0; c < 512; ++c) acc += xa[c] * h1w[c * 128 + t];
  h1s[t] = fmaxf(acc, 0.f);
  __syncthreads();
  if (t < 8) {
    float a2 = h2b[t];
    for (int j = 0; j < 128; ++j) a2 += h1s[j] * h2w[j * 8 + t];
    hw[t] = a2;
  }
  __syncthreads();
  float s = 0.f;
#pragma unroll
  for (int h = 0; h < 8; ++h) s += hw[h] * hw[h];
  float Tb = tsum[b];
  const float aw2 = (1.f / (1.f + __expf(-freqw[0]))) * LOG2E;
  for (int n = t; n < 1024; n += 128) {
    float dn = dfeat[b * 1024 + n];
    float p = s * dn;
    crow[b * 1024 + n] = aw2 * p / fmaxf(p * Tb, 1e-5f);
  }
}

// ---------- weight transpose+convert: w (K,Nw) f32 -> wt (Nw,512) bf16 ----------
__global__ __launch_bounds__(256) void k_wtrans(const float* __restrict__ w,
                                                unsigned short* __restrict__ wt,
                                                int Nw) {
  __shared__ unsigned short T[64 * 65];
  int n0 = blockIdx.x * 64, k0 = blockIdx.y * 64;
  int t = threadIdx.x;
  int r = t >> 2, c0 = (t & 3) * 16;
  const float* src = w + (size_t)(k0 + r) * Nw + n0 + c0;
#pragma unroll
  for (int q = 0; q < 4; ++q) {
    float4 v4 = *(const float4*)(src + q * 4);
    T[(c0 + q * 4 + 0) * 65 + r] = f2bf(v4.x);
    T[(c0 + q * 4 + 1) * 65 + r] = f2bf(v4.y);
    T[(c0 + q * 4 + 2) * 65 + r] = f2bf(v4.z);
    T[(c0 + q * 4 + 3) * 65 + r] = f2bf(v4.w);
  }
  __syncthreads();
  int nl = t >> 2, koff = (t & 3) * 16;
  ushort8 o0, o1;
#pragma unroll
  for (int e = 0; e < 8; ++e) o0[e] = T[nl * 65 + koff + e];
#pragma unroll
  for (int e = 0; e < 8; ++e) o1[e] = T[nl * 65 + koff + 8 + e];
  unsigned short* dst = wt + (size_t)(n0 + nl) * 512 + k0 + koff;
  *(ushort8*)(dst) = o0;
  *(ushort8*)(dst + 8) = o1;
}

// ---------- bf16 MFMA GEMM, 128x128, BK=64, gload_lds + XOR preswizzle --------
// 2D-chunked XCD swizzle: each XCD owns a 16-row-panel stripe.
// MODE 0: QKV epilogue; V written DIRECTLY TRANSPOSED to vtg via LDS transpose.
// MODE 1: proj epilogue (bias, f32 out row-major)
template <int MODE>
__global__ __launch_bounds__(256) void k_gemm(const unsigned short* __restrict__ A,
                                              const unsigned short* __restrict__ Bt,
                                              const float* __restrict__ bias,
                                              const float* __restrict__ freqw,
                                              unsigned short* __restrict__ o_q,
                                              unsigned short* __restrict__ o_k,
                                              unsigned short* __restrict__ o_vt,
                                              float* __restrict__ o_f) {
  __shared__ __align__(16) unsigned short As[128 * 64];
  __shared__ __align__(16) unsigned short Bs[128 * 64];
  const int t = threadIdx.x, w = t >> 6, l = t & 63;
  const int lg = l >> 4, ln = l & 15;
  const int wm = w >> 1, wn = w & 1;
  constexpr int NX = (MODE == 0) ? 12 : 4;
  const int bid = blockIdx.x, xcd = bid & 7, idx = bid >> 3;
  const int bx = idx % NX, by = xcd * 16 + idx / NX;
  const int row0 = by * 128, col0 = bx * 128;

  f32x4 acc[4][4];
#pragma unroll
  for (int i = 0; i < 4; ++i)
#pragma unroll
    for (int j = 0; j < 4; ++j) acc[i][j] = (f32x4){0.f, 0.f, 0.f, 0.f};

  int aoff[4][2], boff[4][2];
#pragma unroll
  for (int mt = 0; mt < 4; ++mt)
#pragma unroll
    for (int ks = 0; ks < 2; ++ks) {
      int ra = wm * 64 + mt * 16 + ln;
      aoff[mt][ks] = ra * 64 + (((lg + ks * 4) ^ (ra & 7)) << 3);
      int rb = wn * 64 + mt * 16 + ln;
      boff[mt][ks] = rb * 64 + (((lg + ks * 4) ^ (rb & 7)) << 3);
    }

  for (int k0 = 0; k0 < 512; k0 += 64) {
#pragma unroll
    for (int j = 0; j < 4; ++j) {
      int g = (j * 4 + w) * 64 + l;
      int row = g >> 3, slot = g & 7;
      int ss = slot ^ (row & 7);
      GLOAD16(A + (size_t)(row0 + row) * 512 + k0 + ss * 8, As + (size_t)(j * 4 + w) * 512);
      GLOAD16(Bt + (size_t)(col0 + row) * 512 + k0 + ss * 8, Bs + (size_t)(j * 4 + w) * 512);
    }
    __syncthreads();
#pragma unroll
    for (int ks = 0; ks < 2; ++ks) {
      bf16x8 av[4], bv[4];
#pragma unroll
      for (int mt = 0; mt < 4; ++mt) av[mt] = *(const bf16x8*)(As + aoff[mt][ks]);
#pragma unroll
      for (int nt = 0; nt < 4; ++nt) bv[nt] = *(const bf16x8*)(Bs + boff[nt][ks]);
#pragma unroll
      for (int mt = 0; mt < 4; ++mt)
#pragma unroll
        for (int nt = 0; nt < 4; ++nt)
          acc[mt][nt] = __builtin_amdgcn_mfma_f32_16x16x32_bf16(av[mt], bv[nt], acc[mt][nt], 0, 0, 0);
    }
    __syncthreads();
  }

  if (MODE == 0) {
    const int sel = col0 >> 9;
    if (sel == 2) {
      // V: bias + f2bf, transposed LDS store (XOR-swizzled), coalesced to vtg
      unsigned short* T = (wn == 0) ? As : Bs;
#pragma unroll
      for (int nt = 0; nt < 4; ++nt) {
        int dcol = nt * 16 + ln;  // 0..63 within half
        float bcol = bias[col0 + wn * 64 + dcol];
#pragma unroll
        for (int mt = 0; mt < 4; ++mt)
#pragma unroll
          for (int r = 0; r < 4; ++r) {
            int rowL = wm * 64 + mt * 16 + lg * 4 + r;
            int slot = (rowL >> 3) ^ (dcol & 7);
            T[dcol * 128 + slot * 8 + (rowL & 7)] = f2bf(acc[mt][nt][r] + bcol);
          }
      }
      __syncthreads();
      int b_ = row0 >> 10, n0 = row0 & 1023;
      int h0 = (col0 & 511) >> 6;
      int dcol = t >> 2, rseg = (t & 3) * 32;
#pragma unroll
      for (int half = 0; half < 2; ++half) {
        const unsigned short* S = half ? Bs : As;
        size_t plane = ((size_t)(b_ * 8 + h0 + half)) << 16;
        unsigned short* dst = o_vt + plane + (size_t)dcol * 1024 + n0 + rseg;
#pragma unroll
        for (int j = 0; j < 4; ++j) {
          int slot = ((rseg >> 3) + j) ^ (dcol & 7);
          *(ushort8*)(dst + j * 8) = *(const ushort8*)(S + dcol * 128 + slot * 8);
        }
      }
      return;
    }
    unsigned short* outp = (sel == 0) ? o_q : o_k;
    const float aw = 1.f / (1.f + __expf(-freqw[0]));
    const float scl = (sel == 0) ? 0.125f * (1.f - aw) * LOG2E : 1.f;
#pragma unroll
    for (int nt = 0; nt < 4; ++nt) {
      int colg = col0 + wn * 64 + nt * 16 + ln;
      float bcol = bias[colg];
      int h = (colg >> 6) & 7, d = colg & 63;
#pragma unroll
      for (int mt = 0; mt < 4; ++mt)
#pragma unroll
        for (int r = 0; r < 4; ++r) {
          int row = row0 + wm * 64 + mt * 16 + lg * 4 + r;
          int bidx = row >> 10, n = row & 1023;
          float val = (acc[mt][nt][r] + bcol) * scl;
          outp[(((size_t)(bidx * 8 + h)) << 16) + (n << 6) + d] = f2bf(val);
        }
    }
  } else {
#pragma unroll
    for (int nt = 0; nt < 4; ++nt) {
      int colg = col0 + wn * 64 + nt * 16 + ln;
      float bcol = bias[colg];
#pragma unroll
      for (int mt = 0; mt < 4; ++mt)
#pragma unroll
        for (int r = 0; r < 4; ++r) {
          int row = row0 + wm * 64 + mt * 16 + lg * 4 + r;
          o_f[(size_t)row * 512 + colg] = acc[mt][nt][r] + bcol;
        }
    }
  }
}

// ---------- flash attention, QBLK=128, XCD-local K/V dispatch ----------
__global__ __launch_bounds__(256) void k_attn(const unsigned short* __restrict__ qb,
                                              const unsigned short* __restrict__ kb,
                                              const unsigned short* __restrict__ vtg,
                                              const float* __restrict__ crow,
                                              const float* __restrict__ dfeat,
                                              const float* __restrict__ freqw,
                                              unsigned short* __restrict__ ao) {
  __shared__ __align__(16) unsigned short Ks[64 * 64];
  __shared__ __align__(16) unsigned short Vs[64 * 64];
  __shared__ __align__(16) unsigned short Ps[4][32 * 64];
  // XCD swizzle: all 8 qt-blocks of one (b,h) land on the same XCD (bid%8)
  const int bid = blockIdx.x, xcd = bid & 7, idx = bid >> 3;
  const int bh = xcd * 16 + (idx >> 3), qt = idx & 7;
  const int b = bh >> 3, h = bh & 7;
  const int t = threadIdx.x, w = t >> 6, l = t & 63;
  const int lg = l >> 4, ln = l & 15;
  const size_t base = ((size_t)(b * 8 + h)) << 16;
  const float aw2 = (1.f / (1.f + __expf(-freqw[0]))) * LOG2E;

  const int qrow0 = qt * 128 + w * 32;
  bf16x8 qf[2][2];
#pragma unroll
  for (int mt = 0; mt < 2; ++mt)
#pragma unroll
    for (int ks = 0; ks < 2; ++ks)
      qf[mt][ks] = *(const bf16x8*)(qb + base + (size_t)(qrow0 + mt * 16 + ln) * 64 + lg * 8 + ks * 32);

  float cr2[2][4];
#pragma unroll
  for (int mt = 0; mt < 2; ++mt)
#pragma unroll
    for (int r = 0; r < 4; ++r)
      cr2[mt][r] = crow[b * 1024 + qrow0 + mt * 16 + lg * 4 + r];

  f32x4 accO[2][4];
#pragma unroll
  for (int mt = 0; mt < 2; ++mt)
#pragma unroll
    for (int dt = 0; dt < 4; ++dt) accO[mt][dt] = (f32x4){0.f, 0.f, 0.f, 0.f};
  float mrow[2][4], psum[2][4];
#pragma unroll
  for (int mt = 0; mt < 2; ++mt)
#pragma unroll
    for (int r = 0; r < 4; ++r) { mrow[mt][r] = -1e30f; psum[mt][r] = 0.f; }

  int rdoff[2];
#pragma unroll
  for (int ks = 0; ks < 2; ++ks) rdoff[ks] = ln * 64 + (((lg + ks * 4) ^ (ln & 7)) << 3);
  int pwoff[4][4];
#pragma unroll
  for (int nt = 0; nt < 4; ++nt)
#pragma unroll
    for (int r = 0; r < 4; ++r) {
      int prow = lg * 4 + r;
      pwoff[nt][r] = prow * 64 + ((((nt << 1) | (ln >> 3)) ^ (prow & 7)) << 3) + (ln & 7);
    }

  for (int kt = 0; kt < 16; ++kt) {
    __syncthreads();
#pragma unroll
    for (int j = 0; j < 2; ++j) {
      int g = (j * 4 + w) * 64 + l;
      int row = g >> 3, slot = g & 7;
      int ss = slot ^ (row & 7);
      GLOAD16(kb + base + (size_t)(kt * 64 + row) * 64 + ss * 8, Ks + (size_t)(j * 4 + w) * 512);
      GLOAD16(vtg + base + (size_t)row * 1024 + kt * 64 + ss * 8, Vs + (size_t)(j * 4 + w) * 512);
    }
    __syncthreads();

    float dmv[4];
#pragma unroll
    for (int nt = 0; nt < 4; ++nt) dmv[nt] = dfeat[b * 1024 + kt * 64 + nt * 16 + ln];
    f32x4 s[2][4];
#pragma unroll
    for (int mt = 0; mt < 2; ++mt)
#pragma unroll
      for (int nt = 0; nt < 4; ++nt)
#pragma unroll
        for (int r = 0; r < 4; ++r)
          s[mt][nt][r] = fminf(fmaxf(cr2[mt][r] * dmv[nt], 0.f), aw2);
#pragma unroll
    for (int nt = 0; nt < 4; ++nt) {
      bf16x8 kf0 = *(const bf16x8*)(Ks + nt * 1024 + rdoff[0]);
      bf16x8 kf1 = *(const bf16x8*)(Ks + nt * 1024 + rdoff[1]);
#pragma unroll
      for (int mt = 0; mt < 2; ++mt) {
        s[mt][nt] = __builtin_amdgcn_mfma_f32_16x16x32_bf16(qf[mt][0], kf0, s[mt][nt], 0, 0, 0);
        s[mt][nt] = __builtin_amdgcn_mfma_f32_16x16x32_bf16(qf[mt][1], kf1, s[mt][nt], 0, 0, 0);
      }
    }

    float lmax[2][4];
    bool viol = false;
#pragma unroll
    for (int mt = 0; mt < 2; ++mt)
#pragma unroll
      for (int r = 0; r < 4; ++r) {
        lmax[mt][r] = fmaxf(fmaxf(s[mt][0][r], s[mt][1][r]), fmaxf(s[mt][2][r], s[mt][3][r]));
        viol = viol || (lmax[mt][r] > mrow[mt][r] + 8.f);
      }
    if (__any(viol)) {
#pragma unroll
      for (int mt = 0; mt < 2; ++mt)
#pragma unroll
        for (int r = 0; r < 4; ++r) {
          float pmax = lmax[mt][r];
          pmax = fmaxf(pmax, __shfl_xor(pmax, 1));
          pmax = fmaxf(pmax, __shfl_xor(pmax, 2));
          pmax = fmaxf(pmax, __shfl_xor(pmax, 4));
          pmax = fmaxf(pmax, __shfl_xor(pmax, 8));
          float mnew = fmaxf(mrow[mt][r], pmax);
          float sc = exp2f(mrow[mt][r] - mnew);
          psum[mt][r] *= sc;
          mrow[mt][r] = mnew;
#pragma unroll
          for (int dt = 0; dt < 4; ++dt) accO[mt][dt][r] *= sc;
        }
    }
#pragma unroll
    for (int mt = 0; mt < 2; ++mt)
#pragma unroll
      for (int r = 0; r < 4; ++r) {
        float p0 = exp2f(s[mt][0][r] - mrow[mt][r]);
        float p1 = exp2f(s[mt][1][r] - mrow[mt][r]);
        float p2 = exp2f(s[mt][2][r] - mrow[mt][r]);
        float p3 = exp2f(s[mt][3][r] - mrow[mt][r]);
        psum[mt][r] += (p0 + p1) + (p2 + p3);
        Ps[w][mt * 1024 + pwoff[0][r]] = f2bf_hw(p0);
        Ps[w][mt * 1024 + pwoff[1][r]] = f2bf_hw(p1);
        Ps[w][mt * 1024 + pwoff[2][r]] = f2bf_hw(p2);
        Ps[w][mt * 1024 + pwoff[3][r]] = f2bf_hw(p3);
      }

    bf16x8 pa[2][2];
#pragma unroll
    for (int mt = 0; mt < 2; ++mt)
#pragma unroll
      for (int ks = 0; ks < 2; ++ks)
        pa[mt][ks] = *(const bf16x8*)(Ps[w] + mt * 1024 + rdoff[ks]);
#pragma unroll
    for (int dt = 0; dt < 4; ++dt) {
      bf16x8 vf0 = *(const bf16x8*)(Vs + dt * 1024 + rdoff[0]);
      bf16x8 vf1 = *(const bf16x8*)(Vs + dt * 1024 + rdoff[1]);
#pragma unroll
      for (int mt = 0; mt < 2; ++mt) {
        accO[mt][dt] = __builtin_amdgcn_mfma_f32_16x16x32_bf16(pa[mt][0], vf0, accO[mt][dt], 0, 0, 0);
        accO[mt][dt] = __builtin_amdgcn_mfma_f32_16x16x32_bf16(pa[mt][1], vf1, accO[mt][dt], 0, 0, 0);
      }
    }
  }

#pragma unroll
  for (int mt = 0; mt < 2; ++mt)
#pragma unroll
    for (int r = 0; r < 4; ++r) {
      float lr = psum[mt][r];
      lr += __shfl_xor(lr, 1);
      lr += __shfl_xor(lr, 2);
      lr += __shfl_xor(lr, 4);
      lr += __shfl_xor(lr, 8);
      float inv = 1.f / lr;
      int n = qrow0 + mt * 16 + lg * 4 + r;
#pragma unroll
      for (int dt = 0; dt < 4; ++dt)
        ao[((size_t)(b * 1024 + n)) * 512 + h * 64 + dt * 16 + ln] = f2bf(accO[mt][dt][r] * inv);
    }
}

extern "C" void kernel_launch(void* const* d_in, const int* in_sizes, int n_in,
                              void* d_out, int out_size, void* d_ws, size_t ws_size,
                              hipStream_t stream) {
  const float* x      = (const float*)d_in[0];
  const float* qkv_w  = (const float*)d_in[1];
  const float* qkv_b  = (const float*)d_in[2];
  const float* proj_w = (const float*)d_in[3];
  const float* proj_b = (const float*)d_in[4];
  const float* h1_w   = (const float*)d_in[5];
  const float* h1_b   = (const float*)d_in[6];
  const float* h2_w   = (const float*)d_in[7];
  const float* h2_b   = (const float*)d_in[8];
  const float* freq_w = (const float*)d_in[9];

  char* ws = (char*)d_ws;
  unsigned short* xb  = (unsigned short*)(ws + OFF_XB);
  unsigned short* qbp = (unsigned short*)(ws + OFF_QB);
  unsigned short* kbp = (unsigned short*)(ws + OFF_KB);
  unsigned short* vtg = (unsigned short*)(ws + OFF_VT);
  unsigned short* ao  = (unsigned short*)(ws + OFF_AO);
  unsigned short* wt  = (unsigned short*)(ws + OFF_WT);
  unsigned short* pwt = (unsigned short*)(ws + OFF_PWT);
  float* xmean = (float*)(ws + OFF_XM);
  float* xavg  = (float*)(ws + OFF_XA);
  float* dfeat = (float*)(ws + OFF_DF);
  float* tsum  = (float*)(ws + OFF_TS);
  float* crow  = (float*)(ws + OFF_CR);
  float* out   = (float*)d_out;

  hipMemsetAsync(xavg, 0, 16 * 512 * sizeof(float), stream);

  k_xmean_cvt<<<dim3(4096), 256, 0, stream>>>(x, xmean, xb);
  k_xavg<<<dim3(16, 16), 512, 0, stream>>>(xb, xavg);
  k_dct<<<dim3(16), 1024, 0, stream>>>(xmean, dfeat, tsum);
  k_headw<<<dim3(16), 128, 0, stream>>>(xavg, h1_w, h1_b, h2_w, h2_b, dfeat, tsum, freq_w, crow);
  k_wtrans<<<dim3(24, 8), 256, 0, stream>>>(qkv_w, wt, 1536);
  k_wtrans<<<dim3(8, 8), 256, 0, stream>>>(proj_w, pwt, 512);
  k_gemm<0><<<dim3(12 * 128), 256, 0, stream>>>(xb, wt, qkv_b, freq_w, qbp, kbp, vtg, nullptr);
  k_attn<<<dim3(1024), 256, 0, stream>>>(qbp, kbp, vtg, crow, dfeat, freq_w, ao);
  k_gemm<1><<<dim3(4 * 128), 256, 0, stream>>>(ao, pwt, proj_b, freq_w, nullptr, nullptr, nullptr, out);
}

// Round 10
// 203.506 us; speedup vs baseline: 6.8919x; 1.0038x over previous
//
#include <hip/hip_runtime.h>
#include <hip/hip_bf16.h>
#include <math.h>

#define PI_F  3.14159265358979323846f
#define LOG2E 1.44269504088896340736f

typedef __attribute__((ext_vector_type(8))) short          bf16x8;
typedef __attribute__((ext_vector_type(8))) unsigned short ushort8;
typedef __attribute__((ext_vector_type(4))) float          f32x4;

__device__ __forceinline__ unsigned short f2bf(float f) {
  union { float f; unsigned u; } v; v.f = f;
  unsigned r = v.u + 0x7fffu + ((v.u >> 16) & 1u);
  return (unsigned short)(r >> 16);
}

__device__ __forceinline__ unsigned short f2bf_hw(float f) {
  __hip_bfloat16 h = __float2bfloat16(f);
  return *reinterpret_cast<unsigned short*>(&h);
}

#define GLOAD16(g, l)                                                         \
  __builtin_amdgcn_global_load_lds(                                           \
      (const __attribute__((address_space(1))) void*)(g),                     \
      (__attribute__((address_space(3))) void*)(l), 16, 0, 0)

// ---- workspace layout (BYTE offsets; bf16 = 2 B/elem) ----
static const size_t OFF_XB  = 0;           // bf16 x      (16384,512)   16 MB
static const size_t OFF_QB  = 16777216;    // bf16 q*qscl (B,H,N,64)    16 MB
static const size_t OFF_KB  = 33554432;    // bf16 k                    16 MB
static const size_t OFF_VT  = 67108864;    // bf16 v^T    (B,H,64,N)    16 MB
static const size_t OFF_AO  = 83886080;    // bf16 attn out (16384,512) 16 MB
static const size_t OFF_WT  = 100663296;   // bf16 qkv_w^T (1536,512)  1.5 MB
static const size_t OFF_PWT = 102236160;   // bf16 proj_w^T (512,512)  0.5 MB
static const size_t OFF_XM  = 102760448;   // f32 xmean (B,N)
static const size_t OFF_XA  = 102825984;   // f32 xavg  (B,512)
static const size_t OFF_DF  = 102858752;   // f32 dfeat (B,N)
static const size_t OFF_TS  = 102924288;   // f32 tsum  (B)
static const size_t OFF_CR  = 102924352;   // f32 crow2 (B,N)  [pre-scaled by aw*log2e]

// ---------- x row-mean + f32->bf16 convert ----------
__global__ __launch_bounds__(256) void k_xmean_cvt(const float* __restrict__ x,
                                                   float* __restrict__ xmean,
                                                   unsigned short* __restrict__ xb) {
  int row  = blockIdx.x * 4 + (threadIdx.x >> 6);
  int lane = threadIdx.x & 63;
  const float* px = x + (size_t)row * 512 + lane * 8;
  float4 a = ((const float4*)px)[0];
  float4 b = ((const float4*)px)[1];
  ushort8 o;
  o[0] = f2bf(a.x); o[1] = f2bf(a.y); o[2] = f2bf(a.z); o[3] = f2bf(a.w);
  o[4] = f2bf(b.x); o[5] = f2bf(b.y); o[6] = f2bf(b.z); o[7] = f2bf(b.w);
  *(ushort8*)(xb + (size_t)row * 512 + lane * 8) = o;
  float s = a.x + a.y + a.z + a.w + b.x + b.y + b.z + b.w;
  for (int off = 32; off; off >>= 1) s += __shfl_down(s, off);
  if (lane == 0) xmean[row] = s * (1.f / 512.f);
}

// ---------- x column sums over N from bf16 xb (partial, atomic) ----------
__global__ __launch_bounds__(512) void k_xavg(const unsigned short* __restrict__ xb,
                                              float* __restrict__ xavg) {
  int b = blockIdx.x, chunk = blockIdx.y;
  int c = threadIdx.x;
  const unsigned short* px = xb + ((size_t)b * 1024 + (size_t)chunk * 64) * 512 + c;
  float s = 0.f;
#pragma unroll 8
  for (int n = 0; n < 64; ++n) {
    unsigned u = (unsigned)px[(size_t)n * 512] << 16;
    s += *reinterpret_cast<float*>(&u);
  }
  atomicAdd(&xavg[b * 512 + c], s);
}

// ---------- DCT feature ----------
__global__ __launch_bounds__(1024) void k_dct(const float* __restrict__ xmean,
                                              float* __restrict__ dfeat,
                                              float* __restrict__ tsum) {
  __shared__ float A[32][33], Dm[32][33], Tm[32][33];
  __shared__ float red[1024];
  __shared__ float nrm;
  int b = blockIdx.x, t = threadIdx.x;
  int kk = t >> 5, nn = t & 31;
  A[kk][nn] = xmean[b * 1024 + t];
  float dv = (kk == 0) ? sqrtf(1.f / 32.f)
                       : sqrtf(2.f / 32.f) * cosf(PI_F * (2.f * nn + 1.f) * (float)kk / 64.f);
  Dm[kk][nn] = dv;
  __syncthreads();
  float acc = 0.f;
  for (int m = 0; m < 32; ++m) acc += Dm[kk][m] * A[m][nn];
  Tm[kk][nn] = acc;
  __syncthreads();
  float acc2 = 0.f;
  for (int n = 0; n < 32; ++n) acc2 += Tm[kk][n] * Dm[nn][n];
  float val = fminf(fmaxf(acc2, -10.f), 10.f);
  red[t] = val * val;
  __syncthreads();
  for (int s = 512; s; s >>= 1) { if (t < s) red[t] += red[t + s]; __syncthreads(); }
  if (t == 0) nrm = sqrtf(red[0]) + 1e-5f;
  __syncthreads();
  float dn = val / nrm;
  dfeat[b * 1024 + t] = dn;
  red[t] = dn;
  __syncthreads();
  for (int s = 512; s; s >>= 1) { if (t < s) red[t] += red[t + s]; __syncthreads(); }
  if (t == 0) tsum[b] = red[0];
}

// ---------- head MLP -> row coefficients (pre-scaled by aw*log2e) ----------
__global__ __launch_bounds__(128) void k_headw(const float* __restrict__ xavg,
                                               const float* __restrict__ h1w,
                                               const float* __restrict__ h1b,
                                               const float* __restrict__ h2w,
                                               const float* __restrict__ h2b,
                                               const float* __restrict__ dfeat,
                                               const float* __restrict__ tsum,
                                               const float* __restrict__ freqw,
                                               float* __restrict__ crow) {
  __shared__ float xa[512];
  __shared__ float h1s[128];
  __shared__ float hw[8];
  int b = blockIdx.x, t = threadIdx.x;
  for (int i = t; i < 512; i += 128) xa[i] = xavg[b * 512 + i] * (1.f / 1024.f);
  __syncthreads();
  float acc = h1b[t];
  for (int c = 0; c < 512; ++c) acc += xa[c] * h1w[c * 128 + t];
  h1s[t] = fmaxf(acc, 0.f);
  __syncthreads();
  if (t < 8) {
    float a2 = h2b[t];
    for (int j = 0; j < 128; ++j) a2 += h1s[j] * h2w[j * 8 + t];
    hw[t] = a2;
  }
  __syncthreads();
  float s = 0.f;
#pragma unroll
  for (int h = 0; h < 8; ++h) s += hw[h] * hw[h];
  float Tb = tsum[b];
  const float aw2 = (1.f / (1.f + __expf(-freqw[0]))) * LOG2E;
  for (int n = t; n < 1024; n += 128) {
    float dn = dfeat[b * 1024 + n];
    float p = s * dn;
    crow[b * 1024 + n] = aw2 * p / fmaxf(p * Tb, 1e-5f);
  }
}

// ---------- weight transpose+convert: w (K,Nw) f32 -> wt (Nw,512) bf16 ----------
__global__ __launch_bounds__(256) void k_wtrans(const float* __restrict__ w,
                                                unsigned short* __restrict__ wt,
                                                int Nw) {
  __shared__ unsigned short T[64 * 65];
  int n0 = blockIdx.x * 64, k0 = blockIdx.y * 64;
  int t = threadIdx.x;
  int r = t >> 2, c0 = (t & 3) * 16;
  const float* src = w + (size_t)(k0 + r) * Nw + n0 + c0;
#pragma unroll
  for (int q = 0; q < 4; ++q) {
    float4 v4 = *(const float4*)(src + q * 4);
    T[(c0 + q * 4 + 0) * 65 + r] = f2bf(v4.x);
    T[(c0 + q * 4 + 1) * 65 + r] = f2bf(v4.y);
    T[(c0 + q * 4 + 2) * 65 + r] = f2bf(v4.z);
    T[(c0 + q * 4 + 3) * 65 + r] = f2bf(v4.w);
  }
  __syncthreads();
  int nl = t >> 2, koff = (t & 3) * 16;
  ushort8 o0, o1;
#pragma unroll
  for (int e = 0; e < 8; ++e) o0[e] = T[nl * 65 + koff + e];
#pragma unroll
  for (int e = 0; e < 8; ++e) o1[e] = T[nl * 65 + koff + 8 + e];
  unsigned short* dst = wt + (size_t)(n0 + nl) * 512 + k0 + koff;
  *(ushort8*)(dst) = o0;
  *(ushort8*)(dst + 8) = o1;
}

// ---------- bf16 MFMA GEMM, 128x128, BK=64, gload_lds + XOR preswizzle --------
// 2D-chunked XCD swizzle. MODE 0: QKV epilogue, V written transposed to vtg.
// MODE 1: proj epilogue (bias, f32 out row-major)
template <int MODE>
__global__ __launch_bounds__(256) void k_gemm(const unsigned short* __restrict__ A,
                                              const unsigned short* __restrict__ Bt,
                                              const float* __restrict__ bias,
                                              const float* __restrict__ freqw,
                                              unsigned short* __restrict__ o_q,
                                              unsigned short* __restrict__ o_k,
                                              unsigned short* __restrict__ o_vt,
                                              float* __restrict__ o_f) {
  __shared__ __align__(16) unsigned short As[128 * 64];
  __shared__ __align__(16) unsigned short Bs[128 * 64];
  const int t = threadIdx.x, w = t >> 6, l = t & 63;
  const int lg = l >> 4, ln = l & 15;
  const int wm = w >> 1, wn = w & 1;
  constexpr int NX = (MODE == 0) ? 12 : 4;
  const int bid = blockIdx.x, xcd = bid & 7, idx = bid >> 3;
  const int bx = idx % NX, by = xcd * 16 + idx / NX;
  const int row0 = by * 128, col0 = bx * 128;

  f32x4 acc[4][4];
#pragma unroll
  for (int i = 0; i < 4; ++i)
#pragma unroll
    for (int j = 0; j < 4; ++j) acc[i][j] = (f32x4){0.f, 0.f, 0.f, 0.f};

  int aoff[4][2], boff[4][2];
#pragma unroll
  for (int mt = 0; mt < 4; ++mt)
#pragma unroll
    for (int ks = 0; ks < 2; ++ks) {
      int ra = wm * 64 + mt * 16 + ln;
      aoff[mt][ks] = ra * 64 + (((lg + ks * 4) ^ (ra & 7)) << 3);
      int rb = wn * 64 + mt * 16 + ln;
      boff[mt][ks] = rb * 64 + (((lg + ks * 4) ^ (rb & 7)) << 3);
    }

  for (int k0 = 0; k0 < 512; k0 += 64) {
#pragma unroll
    for (int j = 0; j < 4; ++j) {
      int g = (j * 4 + w) * 64 + l;
      int row = g >> 3, slot = g & 7;
      int ss = slot ^ (row & 7);
      GLOAD16(A + (size_t)(row0 + row) * 512 + k0 + ss * 8, As + (size_t)(j * 4 + w) * 512);
      GLOAD16(Bt + (size_t)(col0 + row) * 512 + k0 + ss * 8, Bs + (size_t)(j * 4 + w) * 512);
    }
    __syncthreads();
#pragma unroll
    for (int ks = 0; ks < 2; ++ks) {
      bf16x8 av[4], bv[4];
#pragma unroll
      for (int mt = 0; mt < 4; ++mt) av[mt] = *(const bf16x8*)(As + aoff[mt][ks]);
#pragma unroll
      for (int nt = 0; nt < 4; ++nt) bv[nt] = *(const bf16x8*)(Bs + boff[nt][ks]);
#pragma unroll
      for (int mt = 0; mt < 4; ++mt)
#pragma unroll
        for (int nt = 0; nt < 4; ++nt)
          acc[mt][nt] = __builtin_amdgcn_mfma_f32_16x16x32_bf16(av[mt], bv[nt], acc[mt][nt], 0, 0, 0);
    }
    __syncthreads();
  }

  if (MODE == 0) {
    const int sel = col0 >> 9;
    if (sel == 2) {
      unsigned short* T = (wn == 0) ? As : Bs;
#pragma unroll
      for (int nt = 0; nt < 4; ++nt) {
        int dcol = nt * 16 + ln;
        float bcol = bias[col0 + wn * 64 + dcol];
#pragma unroll
        for (int mt = 0; mt < 4; ++mt)
#pragma unroll
          for (int r = 0; r < 4; ++r) {
            int rowL = wm * 64 + mt * 16 + lg * 4 + r;
            int slot = (rowL >> 3) ^ (dcol & 7);
            T[dcol * 128 + slot * 8 + (rowL & 7)] = f2bf(acc[mt][nt][r] + bcol);
          }
      }
      __syncthreads();
      int b_ = row0 >> 10, n0 = row0 & 1023;
      int h0 = (col0 & 511) >> 6;
      int dcol = t >> 2, rseg = (t & 3) * 32;
#pragma unroll
      for (int half = 0; half < 2; ++half) {
        const unsigned short* S = half ? Bs : As;
        size_t plane = ((size_t)(b_ * 8 + h0 + half)) << 16;
        unsigned short* dst = o_vt + plane + (size_t)dcol * 1024 + n0 + rseg;
#pragma unroll
        for (int j = 0; j < 4; ++j) {
          int slot = ((rseg >> 3) + j) ^ (dcol & 7);
          *(ushort8*)(dst + j * 8) = *(const ushort8*)(S + dcol * 128 + slot * 8);
        }
      }
      return;
    }
    unsigned short* outp = (sel == 0) ? o_q : o_k;
    const float aw = 1.f / (1.f + __expf(-freqw[0]));
    const float scl = (sel == 0) ? 0.125f * (1.f - aw) * LOG2E : 1.f;
#pragma unroll
    for (int nt = 0; nt < 4; ++nt) {
      int colg = col0 + wn * 64 + nt * 16 + ln;
      float bcol = bias[colg];
      int h = (colg >> 6) & 7, d = colg & 63;
#pragma unroll
      for (int mt = 0; mt < 4; ++mt)
#pragma unroll
        for (int r = 0; r < 4; ++r) {
          int row = row0 + wm * 64 + mt * 16 + lg * 4 + r;
          int bidx = row >> 10, n = row & 1023;
          float val = (acc[mt][nt][r] + bcol) * scl;
          outp[(((size_t)(bidx * 8 + h)) << 16) + (n << 6) + d] = f2bf(val);
        }
    }
  } else {
#pragma unroll
    for (int nt = 0; nt < 4; ++nt) {
      int colg = col0 + wn * 64 + nt * 16 + ln;
      float bcol = bias[colg];
#pragma unroll
      for (int mt = 0; mt < 4; ++mt)
#pragma unroll
        for (int r = 0; r < 4; ++r) {
          int row = row0 + wm * 64 + mt * 16 + lg * 4 + r;
          o_f[(size_t)row * 512 + colg] = acc[mt][nt][r] + bcol;
        }
    }
  }
}

// ---------- flash attention, QBLK=128, XCD-local, K/V double-buffered ---------
// Stage-after-barrier: loads for tile kt+1 issued right after the barrier, so
// the compiler's vmcnt(0) at the NEXT barrier waits for already-landed loads.
__global__ __launch_bounds__(256) void k_attn(const unsigned short* __restrict__ qb,
                                              const unsigned short* __restrict__ kb,
                                              const unsigned short* __restrict__ vtg,
                                              const float* __restrict__ crow,
                                              const float* __restrict__ dfeat,
                                              const float* __restrict__ freqw,
                                              unsigned short* __restrict__ ao) {
  __shared__ __align__(16) unsigned short Ks[2][64 * 64];
  __shared__ __align__(16) unsigned short Vs[2][64 * 64];
  __shared__ __align__(16) unsigned short Ps[4][32 * 64];
  const int bid = blockIdx.x, xcd = bid & 7, idx = bid >> 3;
  const int bh = xcd * 16 + (idx >> 3), qt = idx & 7;
  const int b = bh >> 3, h = bh & 7;
  const int t = threadIdx.x, w = t >> 6, l = t & 63;
  const int lg = l >> 4, ln = l & 15;
  const size_t base = ((size_t)(b * 8 + h)) << 16;
  const float aw2 = (1.f / (1.f + __expf(-freqw[0]))) * LOG2E;

  // per-thread staging address components (fixed across tiles)
  const int g0 = w * 64 + l, g1 = (4 + w) * 64 + l;
  const int srow0 = g0 >> 3, sslot0 = (g0 & 7) ^ (srow0 & 7);
  const int srow1 = g1 >> 3, sslot1 = (g1 & 7) ^ (srow1 & 7);

  const int qrow0 = qt * 128 + w * 32;
  bf16x8 qf[2][2];
#pragma unroll
  for (int mt = 0; mt < 2; ++mt)
#pragma unroll
    for (int ks = 0; ks < 2; ++ks)
      qf[mt][ks] = *(const bf16x8*)(qb + base + (size_t)(qrow0 + mt * 16 + ln) * 64 + lg * 8 + ks * 32);

  float cr2[2][4];
#pragma unroll
  for (int mt = 0; mt < 2; ++mt)
#pragma unroll
    for (int r = 0; r < 4; ++r)
      cr2[mt][r] = crow[b * 1024 + qrow0 + mt * 16 + lg * 4 + r];

  f32x4 accO[2][4];
#pragma unroll
  for (int mt = 0; mt < 2; ++mt)
#pragma unroll
    for (int dt = 0; dt < 4; ++dt) accO[mt][dt] = (f32x4){0.f, 0.f, 0.f, 0.f};
  float mrow[2][4], psum[2][4];
#pragma unroll
  for (int mt = 0; mt < 2; ++mt)
#pragma unroll
    for (int r = 0; r < 4; ++r) { mrow[mt][r] = -1e30f; psum[mt][r] = 0.f; }

  int rdoff[2];
#pragma unroll
  for (int ks = 0; ks < 2; ++ks) rdoff[ks] = ln * 64 + (((lg + ks * 4) ^ (ln & 7)) << 3);
  int pwoff[4][4];
#pragma unroll
  for (int nt = 0; nt < 4; ++nt)
#pragma unroll
    for (int r = 0; r < 4; ++r) {
      int prow = lg * 4 + r;
      pwoff[nt][r] = prow * 64 + ((((nt << 1) | (ln >> 3)) ^ (prow & 7)) << 3) + (ln & 7);
    }

  // prologue: stage tile 0 into buffer 0
  GLOAD16(kb + base + (size_t)srow0 * 64 + sslot0 * 8, Ks[0] + (size_t)w * 512);
  GLOAD16(vtg + base + (size_t)srow0 * 1024 + sslot0 * 8, Vs[0] + (size_t)w * 512);
  GLOAD16(kb + base + (size_t)srow1 * 64 + sslot1 * 8, Ks[0] + (size_t)(4 + w) * 512);
  GLOAD16(vtg + base + (size_t)srow1 * 1024 + sslot1 * 8, Vs[0] + (size_t)(4 + w) * 512);

  for (int kt = 0; kt < 16; ++kt) {
    const int cur = kt & 1;
    __syncthreads();  // vmcnt(0): buf[cur] ready; all waves done reading buf[cur^1]
    if (kt < 15) {    // stage next tile — overlaps with this tile's compute
      const int kn = kt + 1;
      GLOAD16(kb + base + (size_t)(kn * 64 + srow0) * 64 + sslot0 * 8, Ks[cur ^ 1] + (size_t)w * 512);
      GLOAD16(vtg + base + (size_t)srow0 * 1024 + kn * 64 + sslot0 * 8, Vs[cur ^ 1] + (size_t)w * 512);
      GLOAD16(kb + base + (size_t)(kn * 64 + srow1) * 64 + sslot1 * 8, Ks[cur ^ 1] + (size_t)(4 + w) * 512);
      GLOAD16(vtg + base + (size_t)srow1 * 1024 + kn * 64 + sslot1 * 8, Vs[cur ^ 1] + (size_t)(4 + w) * 512);
    }

    float dmv[4];
#pragma unroll
    for (int nt = 0; nt < 4; ++nt) dmv[nt] = dfeat[b * 1024 + kt * 64 + nt * 16 + ln];
    f32x4 s[2][4];
#pragma unroll
    for (int mt = 0; mt < 2; ++mt)
#pragma unroll
      for (int nt = 0; nt < 4; ++nt)
#pragma unroll
        for (int r = 0; r < 4; ++r)
          s[mt][nt][r] = fminf(fmaxf(cr2[mt][r] * dmv[nt], 0.f), aw2);
#pragma unroll
    for (int nt = 0; nt < 4; ++nt) {
      bf16x8 kf0 = *(const bf16x8*)(Ks[cur] + nt * 1024 + rdoff[0]);
      bf16x8 kf1 = *(const bf16x8*)(Ks[cur] + nt * 1024 + rdoff[1]);
#pragma unroll
      for (int mt = 0; mt < 2; ++mt) {
        s[mt][nt] = __builtin_amdgcn_mfma_f32_16x16x32_bf16(qf[mt][0], kf0, s[mt][nt], 0, 0, 0);
        s[mt][nt] = __builtin_amdgcn_mfma_f32_16x16x32_bf16(qf[mt][1], kf1, s[mt][nt], 0, 0, 0);
      }
    }

    float lmax[2][4];
    bool viol = false;
#pragma unroll
    for (int mt = 0; mt < 2; ++mt)
#pragma unroll
      for (int r = 0; r < 4; ++r) {
        lmax[mt][r] = fmaxf(fmaxf(s[mt][0][r], s[mt][1][r]), fmaxf(s[mt][2][r], s[mt][3][r]));
        viol = viol || (lmax[mt][r] > mrow[mt][r] + 8.f);
      }
    if (__any(viol)) {
#pragma unroll
      for (int mt = 0; mt < 2; ++mt)
#pragma unroll
        for (int r = 0; r < 4; ++r) {
          float pmax = lmax[mt][r];
          pmax = fmaxf(pmax, __shfl_xor(pmax, 1));
          pmax = fmaxf(pmax, __shfl_xor(pmax, 2));
          pmax = fmaxf(pmax, __shfl_xor(pmax, 4));
          pmax = fmaxf(pmax, __shfl_xor(pmax, 8));
          float mnew = fmaxf(mrow[mt][r], pmax);
          float sc = exp2f(mrow[mt][r] - mnew);
          psum[mt][r] *= sc;
          mrow[mt][r] = mnew;
#pragma unroll
          for (int dt = 0; dt < 4; ++dt) accO[mt][dt][r] *= sc;
        }
    }
#pragma unroll
    for (int mt = 0; mt < 2; ++mt)
#pragma unroll
      for (int r = 0; r < 4; ++r) {
        float p0 = exp2f(s[mt][0][r] - mrow[mt][r]);
        float p1 = exp2f(s[mt][1][r] - mrow[mt][r]);
        float p2 = exp2f(s[mt][2][r] - mrow[mt][r]);
        float p3 = exp2f(s[mt][3][r] - mrow[mt][r]);
        psum[mt][r] += (p0 + p1) + (p2 + p3);
        Ps[w][mt * 1024 + pwoff[0][r]] = f2bf_hw(p0);
        Ps[w][mt * 1024 + pwoff[1][r]] = f2bf_hw(p1);
        Ps[w][mt * 1024 + pwoff[2][r]] = f2bf_hw(p2);
        Ps[w][mt * 1024 + pwoff[3][r]] = f2bf_hw(p3);
      }

    bf16x8 pa[2][2];
#pragma unroll
    for (int mt = 0; mt < 2; ++mt)
#pragma unroll
      for (int ks = 0; ks < 2; ++ks)
        pa[mt][ks] = *(const bf16x8*)(Ps[w] + mt * 1024 + rdoff[ks]);
#pragma unroll
    for (int dt = 0; dt < 4; ++dt) {
      bf16x8 vf0 = *(const bf16x8*)(Vs[cur] + dt * 1024 + rdoff[0]);
      bf16x8 vf1 = *(const bf16x8*)(Vs[cur] + dt * 1024 + rdoff[1]);
#pragma unroll
      for (int mt = 0; mt < 2; ++mt) {
        accO[mt][dt] = __builtin_amdgcn_mfma_f32_16x16x32_bf16(pa[mt][0], vf0, accO[mt][dt], 0, 0, 0);
        accO[mt][dt] = __builtin_amdgcn_mfma_f32_16x16x32_bf16(pa[mt][1], vf1, accO[mt][dt], 0, 0, 0);
      }
    }
  }

#pragma unroll
  for (int mt = 0; mt < 2; ++mt)
#pragma unroll
    for (int r = 0; r < 4; ++r) {
      float lr = psum[mt][r];
      lr += __shfl_xor(lr, 1);
      lr += __shfl_xor(lr, 2);
      lr += __shfl_xor(lr, 4);
      lr += __shfl_xor(lr, 8);
      float inv = 1.f / lr;
      int n = qrow0 + mt * 16 + lg * 4 + r;
#pragma unroll
      for (int dt = 0; dt < 4; ++dt)
        ao[((size_t)(b * 1024 + n)) * 512 + h * 64 + dt * 16 + ln] = f2bf(accO[mt][dt][r] * inv);
    }
}

extern "C" void kernel_launch(void* const* d_in, const int* in_sizes, int n_in,
                              void* d_out, int out_size, void* d_ws, size_t ws_size,
                              hipStream_t stream) {
  const float* x      = (const float*)d_in[0];
  const float* qkv_w  = (const float*)d_in[1];
  const float* qkv_b  = (const float*)d_in[2];
  const float* proj_w = (const float*)d_in[3];
  const float* proj_b = (const float*)d_in[4];
  const float* h1_w   = (const float*)d_in[5];
  const float* h1_b   = (const float*)d_in[6];
  const float* h2_w   = (const float*)d_in[7];
  const float* h2_b   = (const float*)d_in[8];
  const float* freq_w = (const float*)d_in[9];

  char* ws = (char*)d_ws;
  unsigned short* xb  = (unsigned short*)(ws + OFF_XB);
  unsigned short* qbp = (unsigned short*)(ws + OFF_QB);
  unsigned short* kbp = (unsigned short*)(ws + OFF_KB);
  unsigned short* vtg = (unsigned short*)(ws + OFF_VT);
  unsigned short* ao  = (unsigned short*)(ws + OFF_AO);
  unsigned short* wt  = (unsigned short*)(ws + OFF_WT);
  unsigned short* pwt = (unsigned short*)(ws + OFF_PWT);
  float* xmean = (float*)(ws + OFF_XM);
  float* xavg  = (float*)(ws + OFF_XA);
  float* dfeat = (float*)(ws + OFF_DF);
  float* tsum  = (float*)(ws + OFF_TS);
  float* crow  = (float*)(ws + OFF_CR);
  float* out   = (float*)d_out;

  hipMemsetAsync(xavg, 0, 16 * 512 * sizeof(float), stream);

  k_xmean_cvt<<<dim3(4096), 256, 0, stream>>>(x, xmean, xb);
  k_xavg<<<dim3(16, 16), 512, 0, stream>>>(xb, xavg);
  k_dct<<<dim3(16), 1024, 0, stream>>>(xmean, dfeat, tsum);
  k_headw<<<dim3(16), 128, 0, stream>>>(xavg, h1_w, h1_b, h2_w, h2_b, dfeat, tsum, freq_w, crow);
  k_wtrans<<<dim3(24, 8), 256, 0, stream>>>(qkv_w, wt, 1536);
  k_wtrans<<<dim3(8, 8), 256, 0, stream>>>(proj_w, pwt, 512);
  k_gemm<0><<<dim3(12 * 128), 256, 0, stream>>>(xb, wt, qkv_b, freq_w, qbp, kbp, vtg, nullptr);
  k_attn<<<dim3(1024), 256, 0, stream>>>(qbp, kbp, vtg, crow, dfeat, freq_w, ao);
  k_gemm<1><<<dim3(4 * 128), 256, 0, stream>>>(ao, pwt, proj_b, freq_w, nullptr, nullptr, nullptr, out);
}

// Round 11
// 187.940 us; speedup vs baseline: 7.4627x; 1.0828x over previous
//
#include <hip/hip_runtime.h>
#include <hip/hip_bf16.h>
#include <math.h>

#define PI_F  3.14159265358979323846f
#define LOG2E 1.44269504088896340736f

typedef __attribute__((ext_vector_type(8))) short          bf16x8;
typedef __attribute__((ext_vector_type(8))) unsigned short ushort8;
typedef __attribute__((ext_vector_type(4))) float          f32x4;

__device__ __forceinline__ unsigned short f2bf(float f) {
  union { float f; unsigned u; } v; v.f = f;
  unsigned r = v.u + 0x7fffu + ((v.u >> 16) & 1u);
  return (unsigned short)(r >> 16);
}

__device__ __forceinline__ unsigned short f2bf_hw(float f) {
  __hip_bfloat16 h = __float2bfloat16(f);
  return *reinterpret_cast<unsigned short*>(&h);
}

#define GLOAD16(g, l)                                                         \
  __builtin_amdgcn_global_load_lds(                                           \
      (const __attribute__((address_space(1))) void*)(g),                     \
      (__attribute__((address_space(3))) void*)(l), 16, 0, 0)

// ---- workspace layout (BYTE offsets; bf16 = 2 B/elem) ----
static const size_t OFF_XB  = 0;           // bf16 x      (16384,512)   16 MB
static const size_t OFF_QB  = 16777216;    // bf16 q*qscl (B,H,N,64)    16 MB
static const size_t OFF_KB  = 33554432;    // bf16 k                    16 MB
static const size_t OFF_VT  = 67108864;    // bf16 v^T    (B,H,64,N)    16 MB
static const size_t OFF_AO  = 83886080;    // bf16 attn out (16384,512) 16 MB
static const size_t OFF_WT  = 100663296;   // bf16 qkv_w^T (1536,512)  1.5 MB
static const size_t OFF_PWT = 102236160;   // bf16 proj_w^T (512,512)  0.5 MB
static const size_t OFF_XM  = 102760448;   // f32 xmean (B,N)
static const size_t OFF_XA  = 102825984;   // f32 xavg  (B,512)
static const size_t OFF_DF  = 102858752;   // f32 dfeat (B,N)
static const size_t OFF_TS  = 102924288;   // f32 tsum  (B)
static const size_t OFF_CR  = 102924352;   // f32 crow2 (B,N)  [pre-scaled by aw*log2e]

// ---------- x row-mean + f32->bf16 convert ----------
__global__ __launch_bounds__(256) void k_xmean_cvt(const float* __restrict__ x,
                                                   float* __restrict__ xmean,
                                                   unsigned short* __restrict__ xb) {
  int row  = blockIdx.x * 4 + (threadIdx.x >> 6);
  int lane = threadIdx.x & 63;
  const float* px = x + (size_t)row * 512 + lane * 8;
  float4 a = ((const float4*)px)[0];
  float4 b = ((const float4*)px)[1];
  ushort8 o;
  o[0] = f2bf(a.x); o[1] = f2bf(a.y); o[2] = f2bf(a.z); o[3] = f2bf(a.w);
  o[4] = f2bf(b.x); o[5] = f2bf(b.y); o[6] = f2bf(b.z); o[7] = f2bf(b.w);
  *(ushort8*)(xb + (size_t)row * 512 + lane * 8) = o;
  float s = a.x + a.y + a.z + a.w + b.x + b.y + b.z + b.w;
  for (int off = 32; off; off >>= 1) s += __shfl_down(s, off);
  if (lane == 0) xmean[row] = s * (1.f / 512.f);
}

// ---------- x column sums over N from bf16 xb (partial, atomic) ----------
__global__ __launch_bounds__(512) void k_xavg(const unsigned short* __restrict__ xb,
                                              float* __restrict__ xavg) {
  int b = blockIdx.x, chunk = blockIdx.y;
  int c = threadIdx.x;
  const unsigned short* px = xb + ((size_t)b * 1024 + (size_t)chunk * 64) * 512 + c;
  float s = 0.f;
#pragma unroll 8
  for (int n = 0; n < 64; ++n) {
    unsigned u = (unsigned)px[(size_t)n * 512] << 16;
    s += *reinterpret_cast<float*>(&u);
  }
  atomicAdd(&xavg[b * 512 + c], s);
}

// ---------- DCT feature ----------
__global__ __launch_bounds__(1024) void k_dct(const float* __restrict__ xmean,
                                              float* __restrict__ dfeat,
                                              float* __restrict__ tsum) {
  __shared__ float A[32][33], Dm[32][33], Tm[32][33];
  __shared__ float red[1024];
  __shared__ float nrm;
  int b = blockIdx.x, t = threadIdx.x;
  int kk = t >> 5, nn = t & 31;
  A[kk][nn] = xmean[b * 1024 + t];
  float dv = (kk == 0) ? sqrtf(1.f / 32.f)
                       : sqrtf(2.f / 32.f) * cosf(PI_F * (2.f * nn + 1.f) * (float)kk / 64.f);
  Dm[kk][nn] = dv;
  __syncthreads();
  float acc = 0.f;
  for (int m = 0; m < 32; ++m) acc += Dm[kk][m] * A[m][nn];
  Tm[kk][nn] = acc;
  __syncthreads();
  float acc2 = 0.f;
  for (int n = 0; n < 32; ++n) acc2 += Tm[kk][n] * Dm[nn][n];
  float val = fminf(fmaxf(acc2, -10.f), 10.f);
  red[t] = val * val;
  __syncthreads();
  for (int s = 512; s; s >>= 1) { if (t < s) red[t] += red[t + s]; __syncthreads(); }
  if (t == 0) nrm = sqrtf(red[0]) + 1e-5f;
  __syncthreads();
  float dn = val / nrm;
  dfeat[b * 1024 + t] = dn;
  red[t] = dn;
  __syncthreads();
  for (int s = 512; s; s >>= 1) { if (t < s) red[t] += red[t + s]; __syncthreads(); }
  if (t == 0) tsum[b] = red[0];
}

// ---------- head MLP -> row coefficients (pre-scaled by aw*log2e) ----------
__global__ __launch_bounds__(128) void k_headw(const float* __restrict__ xavg,
                                               const float* __restrict__ h1w,
                                               const float* __restrict__ h1b,
                                               const float* __restrict__ h2w,
                                               const float* __restrict__ h2b,
                                               const float* __restrict__ dfeat,
                                               const float* __restrict__ tsum,
                                               const float* __restrict__ freqw,
                                               float* __restrict__ crow) {
  __shared__ float xa[512];
  __shared__ float h1s[128];
  __shared__ float hw[8];
  int b = blockIdx.x, t = threadIdx.x;
  for (int i = t; i < 512; i += 128) xa[i] = xavg[b * 512 + i] * (1.f / 1024.f);
  __syncthreads();
  float acc = h1b[t];
  for (int c = 0; c < 512; ++c) acc += xa[c] * h1w[c * 128 + t];
  h1s[t] = fmaxf(acc, 0.f);
  __syncthreads();
  if (t < 8) {
    float a2 = h2b[t];
    for (int j = 0; j < 128; ++j) a2 += h1s[j] * h2w[j * 8 + t];
    hw[t] = a2;
  }
  __syncthreads();
  float s = 0.f;
#pragma unroll
  for (int h = 0; h < 8; ++h) s += hw[h] * hw[h];
  float Tb = tsum[b];
  const float aw2 = (1.f / (1.f + __expf(-freqw[0]))) * LOG2E;
  for (int n = t; n < 1024; n += 128) {
    float dn = dfeat[b * 1024 + n];
    float p = s * dn;
    crow[b * 1024 + n] = aw2 * p / fmaxf(p * Tb, 1e-5f);
  }
}

// ---------- weight transpose+convert: w (K,Nw) f32 -> wt (Nw,512) bf16 ----------
__global__ __launch_bounds__(256) void k_wtrans(const float* __restrict__ w,
                                                unsigned short* __restrict__ wt,
                                                int Nw) {
  __shared__ unsigned short T[64 * 65];
  int n0 = blockIdx.x * 64, k0 = blockIdx.y * 64;
  int t = threadIdx.x;
  int r = t >> 2, c0 = (t & 3) * 16;
  const float* src = w + (size_t)(k0 + r) * Nw + n0 + c0;
#pragma unroll
  for (int q = 0; q < 4; ++q) {
    float4 v4 = *(const float4*)(src + q * 4);
    T[(c0 + q * 4 + 0) * 65 + r] = f2bf(v4.x);
    T[(c0 + q * 4 + 1) * 65 + r] = f2bf(v4.y);
    T[(c0 + q * 4 + 2) * 65 + r] = f2bf(v4.z);
    T[(c0 + q * 4 + 3) * 65 + r] = f2bf(v4.w);
  }
  __syncthreads();
  int nl = t >> 2, koff = (t & 3) * 16;
  ushort8 o0, o1;
#pragma unroll
  for (int e = 0; e < 8; ++e) o0[e] = T[nl * 65 + koff + e];
#pragma unroll
  for (int e = 0; e < 8; ++e) o1[e] = T[nl * 65 + koff + 8 + e];
  unsigned short* dst = wt + (size_t)(n0 + nl) * 512 + k0 + koff;
  *(ushort8*)(dst) = o0;
  *(ushort8*)(dst + 8) = o1;
}

// ---------- bf16 MFMA GEMM, 128x128, BK=64, gload_lds + XOR preswizzle --------
// 2D-chunked XCD swizzle. MODE 0: QKV epilogue, V written transposed to vtg.
// MODE 1: proj epilogue (bias, f32 out row-major)
template <int MODE>
__global__ __launch_bounds__(256) void k_gemm(const unsigned short* __restrict__ A,
                                              const unsigned short* __restrict__ Bt,
                                              const float* __restrict__ bias,
                                              const float* __restrict__ freqw,
                                              unsigned short* __restrict__ o_q,
                                              unsigned short* __restrict__ o_k,
                                              unsigned short* __restrict__ o_vt,
                                              float* __restrict__ o_f) {
  __shared__ __align__(16) unsigned short As[128 * 64];
  __shared__ __align__(16) unsigned short Bs[128 * 64];
  const int t = threadIdx.x, w = t >> 6, l = t & 63;
  const int lg = l >> 4, ln = l & 15;
  const int wm = w >> 1, wn = w & 1;
  constexpr int NX = (MODE == 0) ? 12 : 4;
  const int bid = blockIdx.x, xcd = bid & 7, idx = bid >> 3;
  const int bx = idx % NX, by = xcd * 16 + idx / NX;
  const int row0 = by * 128, col0 = bx * 128;

  f32x4 acc[4][4];
#pragma unroll
  for (int i = 0; i < 4; ++i)
#pragma unroll
    for (int j = 0; j < 4; ++j) acc[i][j] = (f32x4){0.f, 0.f, 0.f, 0.f};

  int aoff[4][2], boff[4][2];
#pragma unroll
  for (int mt = 0; mt < 4; ++mt)
#pragma unroll
    for (int ks = 0; ks < 2; ++ks) {
      int ra = wm * 64 + mt * 16 + ln;
      aoff[mt][ks] = ra * 64 + (((lg + ks * 4) ^ (ra & 7)) << 3);
      int rb = wn * 64 + mt * 16 + ln;
      boff[mt][ks] = rb * 64 + (((lg + ks * 4) ^ (rb & 7)) << 3);
    }

  for (int k0 = 0; k0 < 512; k0 += 64) {
#pragma unroll
    for (int j = 0; j < 4; ++j) {
      int g = (j * 4 + w) * 64 + l;
      int row = g >> 3, slot = g & 7;
      int ss = slot ^ (row & 7);
      GLOAD16(A + (size_t)(row0 + row) * 512 + k0 + ss * 8, As + (size_t)(j * 4 + w) * 512);
      GLOAD16(Bt + (size_t)(col0 + row) * 512 + k0 + ss * 8, Bs + (size_t)(j * 4 + w) * 512);
    }
    __syncthreads();
#pragma unroll
    for (int ks = 0; ks < 2; ++ks) {
      bf16x8 av[4], bv[4];
#pragma unroll
      for (int mt = 0; mt < 4; ++mt) av[mt] = *(const bf16x8*)(As + aoff[mt][ks]);
#pragma unroll
      for (int nt = 0; nt < 4; ++nt) bv[nt] = *(const bf16x8*)(Bs + boff[nt][ks]);
#pragma unroll
      for (int mt = 0; mt < 4; ++mt)
#pragma unroll
        for (int nt = 0; nt < 4; ++nt)
          acc[mt][nt] = __builtin_amdgcn_mfma_f32_16x16x32_bf16(av[mt], bv[nt], acc[mt][nt], 0, 0, 0);
    }
    __syncthreads();
  }

  if (MODE == 0) {
    const int sel = col0 >> 9;
    if (sel == 2) {
      unsigned short* T = (wn == 0) ? As : Bs;
#pragma unroll
      for (int nt = 0; nt < 4; ++nt) {
        int dcol = nt * 16 + ln;
        float bcol = bias[col0 + wn * 64 + dcol];
#pragma unroll
        for (int mt = 0; mt < 4; ++mt)
#pragma unroll
          for (int r = 0; r < 4; ++r) {
            int rowL = wm * 64 + mt * 16 + lg * 4 + r;
            int slot = (rowL >> 3) ^ (dcol & 7);
            T[dcol * 128 + slot * 8 + (rowL & 7)] = f2bf(acc[mt][nt][r] + bcol);
          }
      }
      __syncthreads();
      int b_ = row0 >> 10, n0 = row0 & 1023;
      int h0 = (col0 & 511) >> 6;
      int dcol = t >> 2, rseg = (t & 3) * 32;
#pragma unroll
      for (int half = 0; half < 2; ++half) {
        const unsigned short* S = half ? Bs : As;
        size_t plane = ((size_t)(b_ * 8 + h0 + half)) << 16;
        unsigned short* dst = o_vt + plane + (size_t)dcol * 1024 + n0 + rseg;
#pragma unroll
        for (int j = 0; j < 4; ++j) {
          int slot = ((rseg >> 3) + j) ^ (dcol & 7);
          *(ushort8*)(dst + j * 8) = *(const ushort8*)(S + dcol * 128 + slot * 8);
        }
      }
      return;
    }
    unsigned short* outp = (sel == 0) ? o_q : o_k;
    const float aw = 1.f / (1.f + __expf(-freqw[0]));
    const float scl = (sel == 0) ? 0.125f * (1.f - aw) * LOG2E : 1.f;
#pragma unroll
    for (int nt = 0; nt < 4; ++nt) {
      int colg = col0 + wn * 64 + nt * 16 + ln;
      float bcol = bias[colg];
      int h = (colg >> 6) & 7, d = colg & 63;
#pragma unroll
      for (int mt = 0; mt < 4; ++mt)
#pragma unroll
        for (int r = 0; r < 4; ++r) {
          int row = row0 + wm * 64 + mt * 16 + lg * 4 + r;
          int bidx = row >> 10, n = row & 1023;
          float val = (acc[mt][nt][r] + bcol) * scl;
          outp[(((size_t)(bidx * 8 + h)) << 16) + (n << 6) + d] = f2bf(val);
        }
    }
  } else {
#pragma unroll
    for (int nt = 0; nt < 4; ++nt) {
      int colg = col0 + wn * 64 + nt * 16 + ln;
      float bcol = bias[colg];
#pragma unroll
      for (int mt = 0; mt < 4; ++mt)
#pragma unroll
        for (int r = 0; r < 4; ++r) {
          int row = row0 + wm * 64 + mt * 16 + lg * 4 + r;
          o_f[(size_t)row * 512 + colg] = acc[mt][nt][r] + bcol;
        }
    }
  }
}

// ---------- flash attention, QBLK=128, XCD-local, native exp2 / med3 ----------
__global__ __launch_bounds__(256) void k_attn(const unsigned short* __restrict__ qb,
                                              const unsigned short* __restrict__ kb,
                                              const unsigned short* __restrict__ vtg,
                                              const float* __restrict__ crow,
                                              const float* __restrict__ dfeat,
                                              const float* __restrict__ freqw,
                                              unsigned short* __restrict__ ao) {
  __shared__ __align__(16) unsigned short Ks[64 * 64];
  __shared__ __align__(16) unsigned short Vs[64 * 64];
  __shared__ __align__(16) unsigned short Ps[4][32 * 64];
  __shared__ __align__(16) float Df[1024];
  const int bid = blockIdx.x, xcd = bid & 7, idx = bid >> 3;
  const int bh = xcd * 16 + (idx >> 3), qt = idx & 7;
  const int b = bh >> 3, h = bh & 7;
  const int t = threadIdx.x, w = t >> 6, l = t & 63;
  const int lg = l >> 4, ln = l & 15;
  const size_t base = ((size_t)(b * 8 + h)) << 16;
  const float aw2 = (1.f / (1.f + __expf(-freqw[0]))) * LOG2E;

  // stage dfeat[b] (4 KB) once; covered by the first in-loop barrier
  *(float4*)(&Df[t * 4]) = *(const float4*)(dfeat + b * 1024 + t * 4);

  const int qrow0 = qt * 128 + w * 32;
  bf16x8 qf[2][2];
#pragma unroll
  for (int mt = 0; mt < 2; ++mt)
#pragma unroll
    for (int ks = 0; ks < 2; ++ks)
      qf[mt][ks] = *(const bf16x8*)(qb + base + (size_t)(qrow0 + mt * 16 + ln) * 64 + lg * 8 + ks * 32);

  float cr2[2][4];
#pragma unroll
  for (int mt = 0; mt < 2; ++mt)
#pragma unroll
    for (int r = 0; r < 4; ++r)
      cr2[mt][r] = crow[b * 1024 + qrow0 + mt * 16 + lg * 4 + r];

  f32x4 accO[2][4];
#pragma unroll
  for (int mt = 0; mt < 2; ++mt)
#pragma unroll
    for (int dt = 0; dt < 4; ++dt) accO[mt][dt] = (f32x4){0.f, 0.f, 0.f, 0.f};
  float mrow[2][4], psum[2][4];
#pragma unroll
  for (int mt = 0; mt < 2; ++mt)
#pragma unroll
    for (int r = 0; r < 4; ++r) { mrow[mt][r] = -1e30f; psum[mt][r] = 0.f; }

  int rdoff[2];
#pragma unroll
  for (int ks = 0; ks < 2; ++ks) rdoff[ks] = ln * 64 + (((lg + ks * 4) ^ (ln & 7)) << 3);
  int pwoff[4][4];
#pragma unroll
  for (int nt = 0; nt < 4; ++nt)
#pragma unroll
    for (int r = 0; r < 4; ++r) {
      int prow = lg * 4 + r;
      pwoff[nt][r] = prow * 64 + ((((nt << 1) | (ln >> 3)) ^ (prow & 7)) << 3) + (ln & 7);
    }

  for (int kt = 0; kt < 16; ++kt) {
    __syncthreads();  // previous tile fully consumed (+ Df staged, first iter)
#pragma unroll
    for (int j = 0; j < 2; ++j) {
      int g = (j * 4 + w) * 64 + l;
      int row = g >> 3, slot = g & 7;
      int ss = slot ^ (row & 7);
      GLOAD16(kb + base + (size_t)(kt * 64 + row) * 64 + ss * 8, Ks + (size_t)(j * 4 + w) * 512);
      GLOAD16(vtg + base + (size_t)row * 1024 + kt * 64 + ss * 8, Vs + (size_t)(j * 4 + w) * 512);
    }
    __syncthreads();

    float dmv[4];
#pragma unroll
    for (int nt = 0; nt < 4; ++nt) dmv[nt] = Df[kt * 64 + nt * 16 + ln];
    f32x4 s[2][4];
#pragma unroll
    for (int mt = 0; mt < 2; ++mt)
#pragma unroll
      for (int nt = 0; nt < 4; ++nt)
#pragma unroll
        for (int r = 0; r < 4; ++r)
          s[mt][nt][r] = __builtin_amdgcn_fmed3f(cr2[mt][r] * dmv[nt], 0.f, aw2);
#pragma unroll
    for (int nt = 0; nt < 4; ++nt) {
      bf16x8 kf0 = *(const bf16x8*)(Ks + nt * 1024 + rdoff[0]);
      bf16x8 kf1 = *(const bf16x8*)(Ks + nt * 1024 + rdoff[1]);
#pragma unroll
      for (int mt = 0; mt < 2; ++mt) {
        s[mt][nt] = __builtin_amdgcn_mfma_f32_16x16x32_bf16(qf[mt][0], kf0, s[mt][nt], 0, 0, 0);
        s[mt][nt] = __builtin_amdgcn_mfma_f32_16x16x32_bf16(qf[mt][1], kf1, s[mt][nt], 0, 0, 0);
      }
    }

    float lmax[2][4];
    bool viol = false;
#pragma unroll
    for (int mt = 0; mt < 2; ++mt)
#pragma unroll
      for (int r = 0; r < 4; ++r) {
        lmax[mt][r] = fmaxf(fmaxf(s[mt][0][r], s[mt][1][r]), fmaxf(s[mt][2][r], s[mt][3][r]));
        viol = viol || (lmax[mt][r] > mrow[mt][r] + 8.f);
      }
    if (__any(viol)) {
#pragma unroll
      for (int mt = 0; mt < 2; ++mt)
#pragma unroll
        for (int r = 0; r < 4; ++r) {
          float pmax = lmax[mt][r];
          pmax = fmaxf(pmax, __shfl_xor(pmax, 1));
          pmax = fmaxf(pmax, __shfl_xor(pmax, 2));
          pmax = fmaxf(pmax, __shfl_xor(pmax, 4));
          pmax = fmaxf(pmax, __shfl_xor(pmax, 8));
          float mnew = fmaxf(mrow[mt][r], pmax);
          float sc = __builtin_amdgcn_exp2f(mrow[mt][r] - mnew);
          psum[mt][r] *= sc;
          mrow[mt][r] = mnew;
#pragma unroll
          for (int dt = 0; dt < 4; ++dt) accO[mt][dt][r] *= sc;
        }
    }
#pragma unroll
    for (int mt = 0; mt < 2; ++mt)
#pragma unroll
      for (int r = 0; r < 4; ++r) {
        float p0 = __builtin_amdgcn_exp2f(s[mt][0][r] - mrow[mt][r]);
        float p1 = __builtin_amdgcn_exp2f(s[mt][1][r] - mrow[mt][r]);
        float p2 = __builtin_amdgcn_exp2f(s[mt][2][r] - mrow[mt][r]);
        float p3 = __builtin_amdgcn_exp2f(s[mt][3][r] - mrow[mt][r]);
        psum[mt][r] += (p0 + p1) + (p2 + p3);
        Ps[w][mt * 1024 + pwoff[0][r]] = f2bf_hw(p0);
        Ps[w][mt * 1024 + pwoff[1][r]] = f2bf_hw(p1);
        Ps[w][mt * 1024 + pwoff[2][r]] = f2bf_hw(p2);
        Ps[w][mt * 1024 + pwoff[3][r]] = f2bf_hw(p3);
      }

    bf16x8 pa[2][2];
#pragma unroll
    for (int mt = 0; mt < 2; ++mt)
#pragma unroll
      for (int ks = 0; ks < 2; ++ks)
        pa[mt][ks] = *(const bf16x8*)(Ps[w] + mt * 1024 + rdoff[ks]);
#pragma unroll
    for (int dt = 0; dt < 4; ++dt) {
      bf16x8 vf0 = *(const bf16x8*)(Vs + dt * 1024 + rdoff[0]);
      bf16x8 vf1 = *(const bf16x8*)(Vs + dt * 1024 + rdoff[1]);
#pragma unroll
      for (int mt = 0; mt < 2; ++mt) {
        accO[mt][dt] = __builtin_amdgcn_mfma_f32_16x16x32_bf16(pa[mt][0], vf0, accO[mt][dt], 0, 0, 0);
        accO[mt][dt] = __builtin_amdgcn_mfma_f32_16x16x32_bf16(pa[mt][1], vf1, accO[mt][dt], 0, 0, 0);
      }
    }
  }

#pragma unroll
  for (int mt = 0; mt < 2; ++mt)
#pragma unroll
    for (int r = 0; r < 4; ++r) {
      float lr = psum[mt][r];
      lr += __shfl_xor(lr, 1);
      lr += __shfl_xor(lr, 2);
      lr += __shfl_xor(lr, 4);
      lr += __shfl_xor(lr, 8);
      float inv = 1.f / lr;
      int n = qrow0 + mt * 16 + lg * 4 + r;
#pragma unroll
      for (int dt = 0; dt < 4; ++dt)
        ao[((size_t)(b * 1024 + n)) * 512 + h * 64 + dt * 16 + ln] = f2bf(accO[mt][dt][r] * inv);
    }
}

extern "C" void kernel_launch(void* const* d_in, const int* in_sizes, int n_in,
                              void* d_out, int out_size, void* d_ws, size_t ws_size,
                              hipStream_t stream) {
  const float* x      = (const float*)d_in[0];
  const float* qkv_w  = (const float*)d_in[1];
  const float* qkv_b  = (const float*)d_in[2];
  const float* proj_w = (const float*)d_in[3];
  const float* proj_b = (const float*)d_in[4];
  const float* h1_w   = (const float*)d_in[5];
  const float* h1_b   = (const float*)d_in[6];
  const float* h2_w   = (const float*)d_in[7];
  const float* h2_b   = (const float*)d_in[8];
  const float* freq_w = (const float*)d_in[9];

  char* ws = (char*)d_ws;
  unsigned short* xb  = (unsigned short*)(ws + OFF_XB);
  unsigned short* qbp = (unsigned short*)(ws + OFF_QB);
  unsigned short* kbp = (unsigned short*)(ws + OFF_KB);
  unsigned short* vtg = (unsigned short*)(ws + OFF_VT);
  unsigned short* ao  = (unsigned short*)(ws + OFF_AO);
  unsigned short* wt  = (unsigned short*)(ws + OFF_WT);
  unsigned short* pwt = (unsigned short*)(ws + OFF_PWT);
  float* xmean = (float*)(ws + OFF_XM);
  float* xavg  = (float*)(ws + OFF_XA);
  float* dfeat = (float*)(ws + OFF_DF);
  float* tsum  = (float*)(ws + OFF_TS);
  float* crow  = (float*)(ws + OFF_CR);
  float* out   = (float*)d_out;

  hipMemsetAsync(xavg, 0, 16 * 512 * sizeof(float), stream);

  k_xmean_cvt<<<dim3(4096), 256, 0, stream>>>(x, xmean, xb);
  k_xavg<<<dim3(16, 16), 512, 0, stream>>>(xb, xavg);
  k_dct<<<dim3(16), 1024, 0, stream>>>(xmean, dfeat, tsum);
  k_headw<<<dim3(16), 128, 0, stream>>>(xavg, h1_w, h1_b, h2_w, h2_b, dfeat, tsum, freq_w, crow);
  k_wtrans<<<dim3(24, 8), 256, 0, stream>>>(qkv_w, wt, 1536);
  k_wtrans<<<dim3(8, 8), 256, 0, stream>>>(proj_w, pwt, 512);
  k_gemm<0><<<dim3(12 * 128), 256, 0, stream>>>(xb, wt, qkv_b, freq_w, qbp, kbp, vtg, nullptr);
  k_attn<<<dim3(1024), 256, 0, stream>>>(qbp, kbp, vtg, crow, dfeat, freq_w, ao);
  k_gemm<1><<<dim3(4 * 128), 256, 0, stream>>>(ao, pwt, proj_b, freq_w, nullptr, nullptr, nullptr, out);
}